// Round 1
// baseline (205.081 us; speedup 1.0000x reference)
//
#include <hip/hip_runtime.h>
#include <math.h>

typedef float f32x4 __attribute__((ext_vector_type(4)));
typedef short s16x8 __attribute__((ext_vector_type(8)));
typedef unsigned short u16x8 __attribute__((ext_vector_type(8)));
typedef unsigned short ushort_t;
typedef unsigned int uint_t;

#define D_MODEL 512
#define N_HEADS 8
#define HEAD_D  64
#define D_FFN   2048

__device__ __forceinline__ float bf2f(unsigned short u) {
  union { unsigned int i; float f; } c; c.i = ((unsigned int)u) << 16; return c.f;
}
__device__ __forceinline__ unsigned short f2bf(float f) {
  union { float f; unsigned int i; } c; c.f = f;
  unsigned int x = c.i;
  return (unsigned short)((x + 0x7FFFu + ((x >> 16) & 1u)) >> 16);
}
__device__ __forceinline__ float ldx(const void* p, size_t i, int f) {
  return f ? ((const float*)p)[i] : bf2f(((const ushort_t*)p)[i]);
}

// ------------------------------------------------- inline dtype detector
// Per-wave redundant replication of the old detect_all logic: every wave
// samples the SAME first min(n/2,256) u32s, so the result is bit-identical
// to the old flags[] values, with no cross-kernel dependency.
__device__ __forceinline__ int detect1(const void* p, int nelem) {
  const int n_u32 = nelem >> 1;
  const int sample = n_u32 < 256 ? n_u32 : 256;
  const int lane = threadIdx.x & 63;
  int c0 = 0, c1 = 0;
  for (int i = lane; i < sample; i += 64) {
    uint_t u = ((const uint_t*)p)[i];
    if (u != 0u) {
      ++c0;
      int e = (u >> 7) & 0xFF;
      if (e >= 0x70 && e <= 0x83) ++c1;
    }
  }
#pragma unroll
  for (int o = 32; o > 0; o >>= 1) { c0 += __shfl_xor(c0, o); c1 += __shfl_xor(c1, o); }
  return (c0 >= 32 && c1 * 4 <= c0) ? 1 : 0;
}

// ------------------------------------------------- legacy detect (fallback path only)
struct DetectArgs { const void* p[14]; int n[14]; };

__global__ __launch_bounds__(256)
void detect_all(DetectArgs a, int* __restrict__ flags) {
  __shared__ int cnt[2];
  const int b = blockIdx.x;
  const int t = threadIdx.x;
  if (b == 1) { if (t == 0) flags[1] = 0; return; }
  if (t == 0) { cnt[0] = 0; cnt[1] = 0; }
  __syncthreads();
  const int n_u32 = a.n[b] >> 1;
  const int sample = n_u32 < 256 ? n_u32 : 256;
  if (t < sample) {
    uint_t u = ((const uint_t*)a.p[b])[t];
    if (u != 0u) {
      atomicAdd(&cnt[0], 1);
      int e = (u >> 7) & 0xFF;
      if (e >= 0x70 && e <= 0x83) atomicAdd(&cnt[1], 1);
    }
  }
  __syncthreads();
  if (t == 0) flags[b] = (cnt[0] >= 32 && cnt[1] * 4 <= cnt[0]) ? 1 : 0;
}

// ------------------------------------------------- direct-to-LDS helper
typedef __attribute__((address_space(3))) unsigned int lds_u32_t;
typedef __attribute__((address_space(1))) const unsigned int glb_u32_t;
__device__ __forceinline__ void llds16(const void* g, void* l) {
  // HW writes LDS at (wave-uniform l) + lane*16; global addr is per-lane.
  __builtin_amdgcn_global_load_lds((glb_u32_t*)g, (lds_u32_t*)l, 16, 0, 0);
}

// ------------------------------------------------- prep: weight convert+transpose AND ln1
// (independent work merged into one launch; each block self-detects dtypes)
struct WDesc { const void* src; ushort_t* dst; int Kd, Nd, n, tile0; };

__global__ __launch_bounds__(256)
void prep_kernel(WDesc w0, WDesc w1, WDesc w2, WDesc w3, int nconv,
                 const void* __restrict__ x, const void* __restrict__ g,
                 const void* __restrict__ b, ushort_t* __restrict__ h1, int xn) {
  __shared__ ushort_t tile[32][33];
  const int blk = blockIdx.x;
  if (blk >= nconv) {
    // ----- ln1 path (4 rows per block)
    const int fx = detect1(x, xn);
    const int fg = detect1(g, D_MODEL);
    const int fb = detect1(b, D_MODEL);
    const int row = (blk - nconv) * 4 + (threadIdx.x >> 6);
    const int lane = threadIdx.x & 63;
    float v[8], sum = 0.f, sq = 0.f;
#pragma unroll
    for (int i = 0; i < 8; ++i) {
      v[i] = ldx(x, (size_t)row * D_MODEL + lane * 8 + i, fx);
      sum += v[i]; sq += v[i] * v[i];
    }
#pragma unroll
    for (int o = 32; o > 0; o >>= 1) { sum += __shfl_xor(sum, o); sq += __shfl_xor(sq, o); }
    const float mu = sum * (1.0f / D_MODEL);
    const float var = sq * (1.0f / D_MODEL) - mu * mu;
    const float rstd = rsqrtf(var + 1e-5f);
#pragma unroll
    for (int i = 0; i < 8; ++i) {
      int c = lane * 8 + i;
      h1[(size_t)row * D_MODEL + c] =
          f2bf((v[i] - mu) * rstd * ldx(g, c, fg) + ldx(b, c, fb));
    }
    return;
  }
  // ----- weight convert+transpose path
  WDesc d = (blk < w1.tile0) ? w0 : (blk < w2.tile0) ? w1 : (blk < w3.tile0) ? w2 : w3;
  const int f = detect1(d.src, d.n);
  const int lt = blk - d.tile0;
  const int tn = d.Nd / 32;
  const int bk = lt / tn, bn = lt % tn;
  const int tx = threadIdx.x & 31, ty = threadIdx.x >> 5;
#pragma unroll
  for (int r = 0; r < 4; ++r) {
    int k = bk * 32 + ty * 4 + r;
    tile[ty * 4 + r][tx] = f2bf(ldx(d.src, (size_t)k * d.Nd + bn * 32 + tx, f));
  }
  __syncthreads();
#pragma unroll
  for (int r = 0; r < 4; ++r) {
    int n = bn * 32 + ty * 4 + r;
    d.dst[(size_t)n * d.Kd + bk * 32 + tx] = tile[tx][ty * 4 + r];
  }
}

// ------------------------------------------------- LN kernels (self-detecting)
__global__ __launch_bounds__(256)
void ln1_kernel(const void* __restrict__ x, const void* __restrict__ g,
                const void* __restrict__ b, ushort_t* __restrict__ out, int xn) {
  const int fx = detect1(x, xn), fg = detect1(g, D_MODEL), fb = detect1(b, D_MODEL);
  const int row = blockIdx.x * 4 + (threadIdx.x >> 6);
  const int lane = threadIdx.x & 63;
  float v[8], sum = 0.f, sq = 0.f;
#pragma unroll
  for (int i = 0; i < 8; ++i) {
    v[i] = ldx(x, (size_t)row * D_MODEL + lane * 8 + i, fx);
    sum += v[i]; sq += v[i] * v[i];
  }
#pragma unroll
  for (int o = 32; o > 0; o >>= 1) { sum += __shfl_xor(sum, o); sq += __shfl_xor(sq, o); }
  const float mu = sum * (1.0f / D_MODEL);
  const float var = sq * (1.0f / D_MODEL) - mu * mu;
  const float rstd = rsqrtf(var + 1e-5f);
#pragma unroll
  for (int i = 0; i < 8; ++i) {
    int c = lane * 8 + i;
    out[(size_t)row * D_MODEL + c] =
        f2bf((v[i] - mu) * rstd * ldx(g, c, fg) + ldx(b, c, fb));
  }
}

__global__ __launch_bounds__(256)
void ln2_kernel(const float* __restrict__ y, const void* __restrict__ g,
                const void* __restrict__ b, ushort_t* __restrict__ out) {
  const int fg = detect1(g, D_MODEL), fb = detect1(b, D_MODEL);
  const int row = blockIdx.x * 4 + (threadIdx.x >> 6);
  const int lane = threadIdx.x & 63;
  float v[8], sum = 0.f, sq = 0.f;
#pragma unroll
  for (int i = 0; i < 8; ++i) {
    v[i] = y[(size_t)row * D_MODEL + lane * 8 + i];
    sum += v[i]; sq += v[i] * v[i];
  }
#pragma unroll
  for (int o = 32; o > 0; o >>= 1) { sum += __shfl_xor(sum, o); sq += __shfl_xor(sq, o); }
  const float mu = sum * (1.0f / D_MODEL);
  const float var = sq * (1.0f / D_MODEL) - mu * mu;
  const float rstd = rsqrtf(var + 1e-5f);
#pragma unroll
  for (int i = 0; i < 8; ++i) {
    int c = lane * 8 + i;
    out[(size_t)row * D_MODEL + c] =
        f2bf((v[i] - mu) * rstd * ldx(g, c, fg) + ldx(b, c, fb));
  }
}

// ------------------------------------------------- MFMA GEMM, BK=64
// NEW this round: double-buffered direct-to-LDS staging (global_load_lds
// width-16) with counted s_waitcnt vmcnt(N) + raw s_barrier (T4-lite) —
// never drains vmcnt(0) in the main loop. LDS is linear [row][64] with the
// XOR swizzle applied BOTH sides (rule #21): the global source slot is
// pre-swizzled (slot^(row&7)) and the ds_read applies the same XOR, so
// reads stay at the b128 structural minimum (8 lanes/16B granule).
// EPI: 0 = +bias -> bf16            1 = gelu(+bias) -> bf16
//      2 = y[off] = v+bias+res      3 = y[off] += v (+bias if addb)
//      4 = out[off] = y[off] + v (+bias if addb; out dtype per probe)
template <int BM, int BN, int EPI>
__global__ __launch_bounds__(256)
void gemm_bt(const ushort_t* __restrict__ A, int lda,
             const ushort_t* __restrict__ BT, int ldb, int K,
             const void* __restrict__ bias, int bias_off, int bias_n,
             const void* __restrict__ res,
             const void* __restrict__ dprobe, int dprobe_n,
             float* __restrict__ yacc,
             ushort_t* __restrict__ out_bf, int ldo, int addb) {
  constexpr int BK = 64;
  constexpr int FM = BM / 32, FN = BN / 32;
  constexpr int ACH = BM / 32;          // A 16B-chunks per thread per stage
  constexpr int BCH = BN / 32;
  constexpr int VM = ACH + BCH;         // vmem ops in flight per stage
  __shared__ __attribute__((aligned(16))) ushort_t As[2][BM][64];
  __shared__ __attribute__((aligned(16))) ushort_t Bs[2][BN][64];

  const int t = threadIdx.x;
  const int lane = t & 63, wave = t >> 6;
  const int wm = wave >> 1, wn = wave & 1;
  const int q = lane >> 4, lm = lane & 15;
  const int m0 = blockIdx.y * BM, n0 = blockIdx.x * BN;

  const int fbias = detect1(bias, bias_n);
  int fres = 0;
  if constexpr (EPI == 2 || EPI == 4) fres = detect1(dprobe, dprobe_n);

  // staging geometry: chunk c = r*256 + t covers LDS row r*32+(t>>3),
  // slot t&7; HW writes LDS linearly (base + lane*16), so the SOURCE slot
  // carries the swizzle: fetch global chunk (row, slot^(row&7)).
  const int srow = t >> 3, sslot = t & 7;
  const int swz = sslot ^ (srow & 7);
  const ushort_t* ag[ACH];
  const ushort_t* bg[BCH];
#pragma unroll
  for (int r = 0; r < ACH; ++r)
    ag[r] = A + (size_t)(m0 + r * 32 + srow) * lda + swz * 8;
#pragma unroll
  for (int r = 0; r < BCH; ++r)
    bg[r] = BT + (size_t)(n0 + r * 32 + srow) * ldb + swz * 8;

  auto stage = [&](int buf, int k0) {
#pragma unroll
    for (int r = 0; r < ACH; ++r)
      llds16(ag[r] + k0, (char*)&As[buf][0][0] + r * 4096 + wave * 1024);
#pragma unroll
    for (int r = 0; r < BCH; ++r)
      llds16(bg[r] + k0, (char*)&Bs[buf][0][0] + r * 4096 + wave * 1024);
  };

  f32x4 acc[FM][FN];
#pragma unroll
  for (int i = 0; i < FM; ++i)
#pragma unroll
    for (int j = 0; j < FN; ++j) acc[i][j] = (f32x4)(0.0f);

  auto frag_mfma = [&](int buf, int kh) {
    s16x8 af[FM], bf[FN];
    const int xo = ((kh * 4 + q) ^ (lm & 7)) << 4;  // swizzled byte offset in row
#pragma unroll
    for (int i = 0; i < FM; ++i)
      af[i] = *(const s16x8*)((const char*)&As[buf][0][0] +
                              (wm * (BM / 2) + i * 16 + lm) * 128 + xo);
#pragma unroll
    for (int j = 0; j < FN; ++j)
      bf[j] = *(const s16x8*)((const char*)&Bs[buf][0][0] +
                              (wn * (BN / 2) + j * 16 + lm) * 128 + xo);
#pragma unroll
    for (int i = 0; i < FM; ++i)
#pragma unroll
      for (int j = 0; j < FN; ++j)
        acc[i][j] = __builtin_amdgcn_mfma_f32_16x16x32_bf16(af[i], bf[j], acc[i][j], 0, 0, 0);
  };

  const int NT = K / BK;
  stage(0, 0);
  int buf = 0;
  for (int it = 0; it < NT; ++it) {
    if (it + 1 < NT) {
      stage(buf ^ 1, (it + 1) * BK);     // next tile's DMA overlaps this tile's MFMA
      // wait only the OLDEST VM loads (current buf); newest VM stay in flight
      if constexpr (VM == 2)
        asm volatile("s_waitcnt vmcnt(2)\n\ts_barrier" ::: "memory");
      else
        asm volatile("s_waitcnt vmcnt(3)\n\ts_barrier" ::: "memory");
    } else {
      asm volatile("s_waitcnt vmcnt(0)\n\ts_barrier" ::: "memory");
    }
    frag_mfma(buf, 0);
    frag_mfma(buf, 1);
    // all waves' ds_reads of buf must retire before buf is re-staged next iter
    asm volatile("s_waitcnt lgkmcnt(0)\n\ts_barrier" ::: "memory");
    buf ^= 1;
  }

#pragma unroll
  for (int i = 0; i < FM; ++i) {
#pragma unroll
    for (int j = 0; j < FN; ++j) {
      const int colg = n0 + wn * (BN / 2) + j * 16 + lm;
      float bb = 0.0f;
      if (EPI <= 2 || addb) bb = ldx(bias, bias_off + colg, fbias);
#pragma unroll
      for (int r = 0; r < 4; ++r) {
        const int rowg = m0 + wm * (BM / 2) + i * 16 + q * 4 + r;
        float v = acc[i][j][r] + bb;
        const size_t off = (size_t)rowg * ldo + colg;
        if constexpr (EPI == 0) {
          out_bf[off] = f2bf(v);
        } else if constexpr (EPI == 1) {
          out_bf[off] = f2bf(0.5f * v * (1.0f + erff(v * 0.70710678f)));
        } else if constexpr (EPI == 2) {
          yacc[off] = v + ldx(res, off, fres);
        } else if constexpr (EPI == 3) {
          yacc[off] += v;
        } else {
          float fin = yacc[off] + v;
          if (fres) ((float*)(void*)out_bf)[off] = fin;
          else      out_bf[off] = f2bf(fin);
        }
      }
    }
  }
}

// ------------------------------------------------- legacy GEMM (fallback path, r6-proven)
template <int BM, int BN, int EPI>
__global__ __launch_bounds__(256)
void gemm_nn(const ushort_t* __restrict__ A, int lda, int K,
             const void* __restrict__ B, int ldb, int brow0, int bcol0,
             const void* __restrict__ bias, int bias_off,
             const void* __restrict__ res,
             float* __restrict__ yacc,
             ushort_t* __restrict__ out_bf, int ldo,
             const int* __restrict__ flags, int iB, int ibias, int ires, int addb) {
  constexpr int BK = 32;
  constexpr int FM = BM / 32, FN = BN / 32;
  __shared__ __attribute__((aligned(16))) ushort_t As[BM][40];
  __shared__ ushort_t Bs[BK][BN + 2];
  const int t = threadIdx.x;
  const int lane = t & 63, wave = t >> 6;
  const int wm = wave >> 1, wn = wave & 1;
  const int m0 = blockIdx.y * BM, n0 = blockIdx.x * BN;
  const int fB = flags[iB], fbias = flags[ibias];
  f32x4 acc[FM][FN];
#pragma unroll
  for (int i = 0; i < FM; ++i)
#pragma unroll
    for (int j = 0; j < FN; ++j) acc[i][j] = (f32x4)(0.0f);
  const int q = lane >> 4, lm = lane & 15;
  const int arow_s = t >> 2, aslot = t & 3;
  for (int k0 = 0; k0 < K; k0 += BK) {
    __syncthreads();
#pragma unroll
    for (int r = 0; r < BM / 64; ++r) {
      int row = r * 64 + arow_s;
      *(u16x8*)&As[row][aslot * 8] =
          *(const u16x8*)(A + (size_t)(m0 + row) * lda + k0 + aslot * 8);
    }
#pragma unroll
    for (int e = 0; e < (BK * BN) / 256; ++e) {
      int id = e * 256 + t;
      int k = id / BN, n = id % BN;
      Bs[k][n] = f2bf(ldx(B, (size_t)(brow0 + k0 + k) * ldb + bcol0 + n0 + n, fB));
    }
    __syncthreads();
    s16x8 af[FM], bf[FN];
#pragma unroll
    for (int i = 0; i < FM; ++i)
      af[i] = *(const s16x8*)&As[wm * (BM / 2) + i * 16 + lm][q * 8];
#pragma unroll
    for (int j = 0; j < FN; ++j) {
      int nl = wn * (BN / 2) + j * 16 + lm;
      u16x8 tmp;
#pragma unroll
      for (int f = 0; f < 8; ++f) tmp[f] = Bs[q * 8 + f][nl];
      bf[j] = __builtin_bit_cast(s16x8, tmp);
    }
#pragma unroll
    for (int i = 0; i < FM; ++i)
#pragma unroll
      for (int j = 0; j < FN; ++j)
        acc[i][j] = __builtin_amdgcn_mfma_f32_16x16x32_bf16(af[i], bf[j], acc[i][j], 0, 0, 0);
  }
#pragma unroll
  for (int i = 0; i < FM; ++i) {
#pragma unroll
    for (int j = 0; j < FN; ++j) {
      const int col = wn * (BN / 2) + j * 16 + lm;
      float bb = 0.0f;
      if (EPI != 3 || addb) bb = ldx(bias, bias_off + n0 + col, fbias);
#pragma unroll
      for (int r = 0; r < 4; ++r) {
        const int rowg = m0 + wm * (BM / 2) + i * 16 + q * 4 + r;
        float v = acc[i][j][r] + bb;
        if constexpr (EPI == 0) {
          out_bf[(size_t)rowg * ldo + n0 + col] = f2bf(v);
        } else if constexpr (EPI == 1) {
          out_bf[(size_t)rowg * ldo + n0 + col] =
              f2bf(0.5f * v * (1.0f + erff(v * 0.70710678f)));
        } else if constexpr (EPI == 2) {
          const size_t off = (size_t)rowg * D_MODEL + n0 + col;
          yacc[off] = v + ldx(res, off, flags[ires]);
        } else {
          const size_t off = (size_t)rowg * D_MODEL + n0 + col;
          yacc[off] += v;
        }
      }
    }
  }
}

// ------------------------------------------------- attention (r14 coalesced-K)
__device__ __forceinline__ int key_index(int s, int j, int S) {
  int p;
  if (j < 64)       p = s + j - 32;
  else if (j < 102) p = s + (j - 83) * 64;
  else              p = ((j - 102) * (S - 1)) / 25;
  return min(max(p, 0), S - 1);
}

__global__ __launch_bounds__(256, 4)
void attn_kernel(const ushort_t* __restrict__ qkv, ushort_t* __restrict__ out, int S) {
  const int wave = threadIdx.x >> 6, lane = threadIdx.x & 63;
  const int pair = blockIdx.x * 4 + wave;   // pair = h*S + s
  const int h = pair / S;
  const int s = pair - h * S;
  const int g = lane >> 3, d8 = (lane & 7) * 8;

  int koff[16];
#pragma unroll
  for (int r = 0; r < 16; ++r)
    koff[r] = key_index(s, r * 8 + g, S) * (3 * D_MODEL);

  u16x8 qv8 = *(const u16x8*)(qkv + (size_t)s * (3 * D_MODEL) + h * HEAD_D + d8);
  float qf[8];
#pragma unroll
  for (int e = 0; e < 8; ++e) qf[e] = bf2f(qv8[e]);

  const ushort_t* kbase = qkv + D_MODEL + h * HEAD_D + d8;
  float pr[16];
  {
    u16x8 kv[8];
#pragma unroll
    for (int r = 0; r < 8; ++r) kv[r] = *(const u16x8*)(kbase + koff[r]);
#pragma unroll
    for (int r = 0; r < 16; ++r) {
      u16x8 cur = kv[r & 7];
      if (r < 8) kv[r & 7] = *(const u16x8*)(kbase + koff[r + 8]);
      float d = 0.f;
#pragma unroll
      for (int e = 0; e < 8; ++e) d += qf[e] * bf2f(cur[e]);
      d += __shfl_xor(d, 1);
      d += __shfl_xor(d, 2);
      d += __shfl_xor(d, 4);
      pr[r] = d * 0.125f;
    }
  }

  float mx = pr[0];
#pragma unroll
  for (int r = 1; r < 16; ++r) mx = fmaxf(mx, pr[r]);
#pragma unroll
  for (int m = 8; m <= 32; m <<= 1) mx = fmaxf(mx, __shfl_xor(mx, m));
  float sm = 0.f;
#pragma unroll
  for (int r = 0; r < 16; ++r) { pr[r] = __expf(pr[r] - mx); sm += pr[r]; }
#pragma unroll
  for (int m = 8; m <= 32; m <<= 1) sm += __shfl_xor(sm, m);
  const float inv = 1.0f / sm;

  const ushort_t* vbase = qkv + 2 * D_MODEL + h * HEAD_D + d8;
  float oacc[8];
#pragma unroll
  for (int e = 0; e < 8; ++e) oacc[e] = 0.f;
  {
    u16x8 vv[8];
#pragma unroll
    for (int r = 0; r < 8; ++r) vv[r] = *(const u16x8*)(vbase + koff[r]);
#pragma unroll
    for (int r = 0; r < 16; ++r) {
      u16x8 cv = vv[r & 7];
      float cp = pr[r] * inv;
      if (r < 8) vv[r & 7] = *(const u16x8*)(vbase + koff[r + 8]);
#pragma unroll
      for (int e = 0; e < 8; ++e) oacc[e] += cp * bf2f(cv[e]);
    }
  }
#pragma unroll
  for (int m = 8; m <= 32; m <<= 1)
#pragma unroll
    for (int e = 0; e < 8; ++e) oacc[e] += __shfl_xor(oacc[e], m);

  if (lane < 8) {
    u16x8 ov;
#pragma unroll
    for (int e = 0; e < 8; ++e) ov[e] = f2bf(oacc[e]);
    *(u16x8*)(out + (size_t)s * D_MODEL + h * HEAD_D + d8) = ov;
  }
}

// ------------------------------------------------- final convert (fallback only)
__global__ __launch_bounds__(256)
void convert_kernel(const float* __restrict__ y, void* __restrict__ out,
                    const int* __restrict__ flags, int n) {
  const int fout = flags[0];
  int i = blockIdx.x * 256 + threadIdx.x;
  if (i < n) {
    float v = y[i];
    if (fout) ((float*)out)[i] = v;
    else      ((ushort_t*)out)[i] = f2bf(v);
  }
}

// ------------------------------------------------- launch
extern "C" void kernel_launch(void* const* d_in, const int* in_sizes, int n_in,
                              void* d_out, int out_size, void* d_ws, size_t ws_size,
                              hipStream_t stream) {
  const int S = in_sizes[0] / D_MODEL;    // 2048
  const size_t sD = (size_t)S * D_MODEL;
  char* ws = (char*)d_ws;

  ushort_t* h1    = (ushort_t*)d_out;
  ushort_t* attnb = (ushort_t*)d_out;
  ushort_t* h2    = (ushort_t*)d_out;

  const size_t MB = 1024 * 1024;
  if (ws_size >= 12 * MB + 64) {
    const int P  = (ws_size >= 20 * MB) ? 1 : 2;
    const int Nc = D_FFN / P;
    char* wbase = ws + (P == 1 ? 12 : 6) * MB;

    ushort_t* qkv   = (ushort_t*)ws;                       // [0,6M)
    float*    y     = (float*)ws;                          // [0,4M) after qkv dies
    ushort_t* gbuf  = (ushort_t*)(ws + 4 * MB);            // S*Nc bf16 (4 or 8 MB)
    ushort_t* wqkvT = (ushort_t*)wbase;                    // 1.5 MB
    ushort_t* woT   = (ushort_t*)(wbase + 1 * MB + 512 * 1024);  // 0.5 MB
    ushort_t* w1T   = (ushort_t*)(wbase + 2 * MB);         // 2 MB
    ushort_t* w2T   = (ushort_t*)(wbase + 4 * MB);         // 2 MB

    WDesc dq  = { d_in[6],  wqkvT, D_MODEL, 3 * D_MODEL, D_MODEL * 3 * D_MODEL, 0 };
    WDesc dwo = { d_in[8],  woT,   D_MODEL, D_MODEL,     D_MODEL * D_MODEL,     768 };
    WDesc dw1 = { d_in[10], w1T,   D_MODEL, D_FFN,       D_MODEL * D_FFN,       1024 };
    WDesc dw2 = { d_in[12], w2T,   D_FFN,   D_MODEL,     D_FFN * D_MODEL,       2048 };

    // K1: weight convert (3072 blocks) + ln1 (S/4 blocks) in ONE launch
    prep_kernel<<<3072 + S / 4, 256, 0, stream>>>(
        dq, dwo, dw1, dw2, 3072, d_in[0], d_in[2], d_in[3], h1, (int)sD);

    // GEMM1: h1 @ wqkv + bqkv -> qkv
    gemm_bt<32, 64, 0><<<dim3(24, S / 32), 256, 0, stream>>>(
        h1, D_MODEL, wqkvT, D_MODEL, D_MODEL, d_in[7], 0, 3 * D_MODEL,
        nullptr, nullptr, 0, nullptr, qkv, 3 * D_MODEL, 1);

    attn_kernel<<<(S * N_HEADS) / 4, 256, 0, stream>>>(qkv, attnb, S);

    // GEMM2: attnb @ wo + bo + x -> y
    gemm_bt<32, 32, 2><<<dim3(16, S / 32), 256, 0, stream>>>(
        attnb, D_MODEL, woT, D_MODEL, D_MODEL, d_in[9], 0, D_MODEL,
        d_in[0], d_in[0], (int)sD, y, nullptr, D_MODEL, 1);

    ln2_kernel<<<S / 4, 256, 0, stream>>>(y, d_in[4], d_in[5], h2);

    if (P == 1) {
      // GEMM3: h2 @ w1 + b1 -> gelu -> gbuf
      gemm_bt<32, 64, 1><<<dim3(D_FFN / 64, S / 32), 256, 0, stream>>>(
          h2, D_MODEL, w1T, D_MODEL, D_MODEL,
          d_in[11], 0, D_FFN, nullptr, nullptr, 0, nullptr, gbuf, D_FFN, 1);
      // GEMM4: out = y + gbuf @ w2 + b2  (K=2048)
      gemm_bt<32, 32, 4><<<dim3(16, S / 32), 256, 0, stream>>>(
          gbuf, D_FFN, w2T, D_FFN, D_FFN, d_in[13], 0, D_MODEL,
          nullptr, d_in[0], (int)sD, y, (ushort_t*)d_out, D_MODEL, 1);
    } else {
      gemm_bt<32, 64, 1><<<dim3(Nc / 64, S / 32), 256, 0, stream>>>(
          h2, D_MODEL, w1T, D_MODEL, D_MODEL,
          d_in[11], 0, D_FFN, nullptr, nullptr, 0, nullptr, gbuf, Nc, 1);
      gemm_bt<32, 32, 3><<<dim3(16, S / 32), 256, 0, stream>>>(
          gbuf, Nc, w2T, D_FFN, Nc, d_in[13], 0, D_MODEL,
          nullptr, nullptr, 0, y, nullptr, D_MODEL, 1);
      gemm_bt<32, 64, 1><<<dim3(Nc / 64, S / 32), 256, 0, stream>>>(
          h2, D_MODEL, w1T + (size_t)Nc * D_MODEL, D_MODEL, D_MODEL,
          d_in[11], Nc, D_FFN, nullptr, nullptr, 0, nullptr, gbuf, Nc, 1);
      gemm_bt<32, 32, 4><<<dim3(16, S / 32), 256, 0, stream>>>(
          gbuf, Nc, w2T + (size_t)Nc, D_FFN, Nc, d_in[13], 0, D_MODEL,
          nullptr, d_in[0], (int)sD, y, (ushort_t*)d_out, D_MODEL, 0);
    }
  } else {
    // fallback: round-6 proven path
    DetectArgs da;
    for (int i = 0; i < 14; ++i) { da.p[i] = d_in[i]; da.n[i] = in_sizes[i]; }
    int P;
    if      (ws_size >= 12ull * MB + 4096) P = 1;
    else if (ws_size >=  8ull * MB + 4096) P = 2;
    else                                   P = 4;
    const int Nc = D_FFN / P;
    const size_t gbuf_bytes = (size_t)S * Nc * 2;
    const size_t qkv_bytes  = 3 * sD * 2;
    const size_t fo = 4ull * sD + gbuf_bytes;
    const size_t flags_pos = (qkv_bytes > fo ? qkv_bytes : fo);

    ushort_t* qkv  = (ushort_t*)ws;
    float*    y    = (float*)ws;
    ushort_t* gbuf = (ushort_t*)(ws + 4 * sD);
    int*      flags = (int*)(ws + flags_pos);

    detect_all<<<14, 256, 0, stream>>>(da, flags);
    ln1_kernel<<<S / 4, 256, 0, stream>>>(d_in[0], d_in[2], d_in[3], h1, (int)sD);
    gemm_nn<128, 128, 0><<<dim3((3 * D_MODEL) / 128, S / 128), 256, 0, stream>>>(
        h1, D_MODEL, D_MODEL, d_in[6], 3 * D_MODEL, 0, 0, d_in[7], 0,
        nullptr, nullptr, qkv, 3 * D_MODEL, flags, 6, 7, 0, 1);
    attn_kernel<<<(S * N_HEADS) / 4, 256, 0, stream>>>(qkv, attnb, S);
    gemm_nn<64, 64, 2><<<dim3(D_MODEL / 64, S / 64), 256, 0, stream>>>(
        attnb, D_MODEL, D_MODEL, d_in[8], D_MODEL, 0, 0, d_in[9], 0,
        d_in[0], y, nullptr, D_MODEL, flags, 8, 9, 0, 1);
    ln2_kernel<<<S / 4, 256, 0, stream>>>(y, d_in[4], d_in[5], h2);
    for (int p = 0; p < P; ++p) {
      if (Nc >= 1024) {
        gemm_nn<128, 128, 1><<<dim3(Nc / 128, S / 128), 256, 0, stream>>>(
            h2, D_MODEL, D_MODEL, d_in[10], D_FFN, 0, p * Nc, d_in[11], p * Nc,
            nullptr, nullptr, gbuf, Nc, flags, 10, 11, 0, 1);
      } else {
        gemm_nn<64, 64, 1><<<dim3(Nc / 64, S / 64), 256, 0, stream>>>(
            h2, D_MODEL, D_MODEL, d_in[10], D_FFN, 0, p * Nc, d_in[11], p * Nc,
            nullptr, nullptr, gbuf, Nc, flags, 10, 11, 0, 1);
      }
      gemm_nn<64, 64, 3><<<dim3(D_MODEL / 64, S / 64), 256, 0, stream>>>(
          gbuf, Nc, Nc, d_in[12], D_MODEL, p * Nc, 0, d_in[13], 0,
          nullptr, y, nullptr, D_MODEL, flags, 12, 13, 0, p == 0 ? 1 : 0);
    }
    convert_kernel<<<(int)((sD + 255) / 256), 256, 0, stream>>>(y, d_out, flags, (int)sD);
  }
}

// Round 2
// 200.597 us; speedup vs baseline: 1.0224x; 1.0224x over previous
//
#include <hip/hip_runtime.h>
#include <math.h>

typedef float f32x4 __attribute__((ext_vector_type(4)));
typedef short s16x8 __attribute__((ext_vector_type(8)));
typedef unsigned short u16x8 __attribute__((ext_vector_type(8)));
typedef unsigned short ushort_t;
typedef unsigned int uint_t;

#define D_MODEL 512
#define N_HEADS 8
#define HEAD_D  64
#define D_FFN   2048

__device__ __forceinline__ float bf2f(unsigned short u) {
  union { unsigned int i; float f; } c; c.i = ((unsigned int)u) << 16; return c.f;
}
__device__ __forceinline__ unsigned short f2bf(float f) {
  union { float f; unsigned int i; } c; c.f = f;
  unsigned int x = c.i;
  return (unsigned short)((x + 0x7FFFu + ((x >> 16) & 1u)) >> 16);
}
__device__ __forceinline__ float ldx(const void* p, size_t i, int f) {
  return f ? ((const float*)p)[i] : bf2f(((const ushort_t*)p)[i]);
}

// ------------------------------------------------- inline dtype detector
// Per-wave redundant replication of the old detect_all logic: every wave
// samples the SAME first min(n/2,256) u32s, so the result is bit-identical
// to the old flags[] values, with no cross-kernel dependency.
__device__ __forceinline__ int detect1(const void* p, int nelem) {
  const int n_u32 = nelem >> 1;
  const int sample = n_u32 < 256 ? n_u32 : 256;
  const int lane = threadIdx.x & 63;
  int c0 = 0, c1 = 0;
  for (int i = lane; i < sample; i += 64) {
    uint_t u = ((const uint_t*)p)[i];
    if (u != 0u) {
      ++c0;
      int e = (u >> 7) & 0xFF;
      if (e >= 0x70 && e <= 0x83) ++c1;
    }
  }
#pragma unroll
  for (int o = 32; o > 0; o >>= 1) { c0 += __shfl_xor(c0, o); c1 += __shfl_xor(c1, o); }
  return (c0 >= 32 && c1 * 4 <= c0) ? 1 : 0;
}

// ------------------------------------------------- legacy detect (fallback path only)
struct DetectArgs { const void* p[14]; int n[14]; };

__global__ __launch_bounds__(256)
void detect_all(DetectArgs a, int* __restrict__ flags) {
  __shared__ int cnt[2];
  const int b = blockIdx.x;
  const int t = threadIdx.x;
  if (b == 1) { if (t == 0) flags[1] = 0; return; }
  if (t == 0) { cnt[0] = 0; cnt[1] = 0; }
  __syncthreads();
  const int n_u32 = a.n[b] >> 1;
  const int sample = n_u32 < 256 ? n_u32 : 256;
  if (t < sample) {
    uint_t u = ((const uint_t*)a.p[b])[t];
    if (u != 0u) {
      atomicAdd(&cnt[0], 1);
      int e = (u >> 7) & 0xFF;
      if (e >= 0x70 && e <= 0x83) atomicAdd(&cnt[1], 1);
    }
  }
  __syncthreads();
  if (t == 0) flags[b] = (cnt[0] >= 32 && cnt[1] * 4 <= cnt[0]) ? 1 : 0;
}

// ------------------------------------------------- prep: weight convert+transpose AND ln1
// (independent work merged into one launch; each block self-detects dtypes)
struct WDesc { const void* src; ushort_t* dst; int Kd, Nd, n, tile0; };

__global__ __launch_bounds__(256)
void prep_kernel(WDesc w0, WDesc w1, WDesc w2, WDesc w3, int nconv,
                 const void* __restrict__ x, const void* __restrict__ g,
                 const void* __restrict__ b, ushort_t* __restrict__ h1, int xn) {
  __shared__ ushort_t tile[32][33];
  const int blk = blockIdx.x;
  if (blk >= nconv) {
    // ----- ln1 path (4 rows per block)
    const int fx = detect1(x, xn);
    const int fg = detect1(g, D_MODEL);
    const int fb = detect1(b, D_MODEL);
    const int row = (blk - nconv) * 4 + (threadIdx.x >> 6);
    const int lane = threadIdx.x & 63;
    float v[8], sum = 0.f, sq = 0.f;
#pragma unroll
    for (int i = 0; i < 8; ++i) {
      v[i] = ldx(x, (size_t)row * D_MODEL + lane * 8 + i, fx);
      sum += v[i]; sq += v[i] * v[i];
    }
#pragma unroll
    for (int o = 32; o > 0; o >>= 1) { sum += __shfl_xor(sum, o); sq += __shfl_xor(sq, o); }
    const float mu = sum * (1.0f / D_MODEL);
    const float var = sq * (1.0f / D_MODEL) - mu * mu;
    const float rstd = rsqrtf(var + 1e-5f);
#pragma unroll
    for (int i = 0; i < 8; ++i) {
      int c = lane * 8 + i;
      h1[(size_t)row * D_MODEL + c] =
          f2bf((v[i] - mu) * rstd * ldx(g, c, fg) + ldx(b, c, fb));
    }
    return;
  }
  // ----- weight convert+transpose path
  WDesc d = (blk < w1.tile0) ? w0 : (blk < w2.tile0) ? w1 : (blk < w3.tile0) ? w2 : w3;
  const int f = detect1(d.src, d.n);
  const int lt = blk - d.tile0;
  const int tn = d.Nd / 32;
  const int bk = lt / tn, bn = lt % tn;
  const int tx = threadIdx.x & 31, ty = threadIdx.x >> 5;
#pragma unroll
  for (int r = 0; r < 4; ++r) {
    int k = bk * 32 + ty * 4 + r;
    tile[ty * 4 + r][tx] = f2bf(ldx(d.src, (size_t)k * d.Nd + bn * 32 + tx, f));
  }
  __syncthreads();
#pragma unroll
  for (int r = 0; r < 4; ++r) {
    int n = bn * 32 + ty * 4 + r;
    d.dst[(size_t)n * d.Kd + bk * 32 + tx] = tile[tx][ty * 4 + r];
  }
}

// ------------------------------------------------- LN kernels (self-detecting)
__global__ __launch_bounds__(256)
void ln1_kernel(const void* __restrict__ x, const void* __restrict__ g,
                const void* __restrict__ b, ushort_t* __restrict__ out, int xn) {
  const int fx = detect1(x, xn), fg = detect1(g, D_MODEL), fb = detect1(b, D_MODEL);
  const int row = blockIdx.x * 4 + (threadIdx.x >> 6);
  const int lane = threadIdx.x & 63;
  float v[8], sum = 0.f, sq = 0.f;
#pragma unroll
  for (int i = 0; i < 8; ++i) {
    v[i] = ldx(x, (size_t)row * D_MODEL + lane * 8 + i, fx);
    sum += v[i]; sq += v[i] * v[i];
  }
#pragma unroll
  for (int o = 32; o > 0; o >>= 1) { sum += __shfl_xor(sum, o); sq += __shfl_xor(sq, o); }
  const float mu = sum * (1.0f / D_MODEL);
  const float var = sq * (1.0f / D_MODEL) - mu * mu;
  const float rstd = rsqrtf(var + 1e-5f);
#pragma unroll
  for (int i = 0; i < 8; ++i) {
    int c = lane * 8 + i;
    out[(size_t)row * D_MODEL + c] =
        f2bf((v[i] - mu) * rstd * ldx(g, c, fg) + ldx(b, c, fb));
  }
}

__global__ __launch_bounds__(256)
void ln2_kernel(const float* __restrict__ y, const void* __restrict__ g,
                const void* __restrict__ b, ushort_t* __restrict__ out) {
  const int fg = detect1(g, D_MODEL), fb = detect1(b, D_MODEL);
  const int row = blockIdx.x * 4 + (threadIdx.x >> 6);
  const int lane = threadIdx.x & 63;
  float v[8], sum = 0.f, sq = 0.f;
#pragma unroll
  for (int i = 0; i < 8; ++i) {
    v[i] = y[(size_t)row * D_MODEL + lane * 8 + i];
    sum += v[i]; sq += v[i] * v[i];
  }
#pragma unroll
  for (int o = 32; o > 0; o >>= 1) { sum += __shfl_xor(sum, o); sq += __shfl_xor(sq, o); }
  const float mu = sum * (1.0f / D_MODEL);
  const float var = sq * (1.0f / D_MODEL) - mu * mu;
  const float rstd = rsqrtf(var + 1e-5f);
#pragma unroll
  for (int i = 0; i < 8; ++i) {
    int c = lane * 8 + i;
    out[(size_t)row * D_MODEL + c] =
        f2bf((v[i] - mu) * rstd * ldx(g, c, fg) + ldx(b, c, fb));
  }
}

// ------------------------------------------------- pipelined MFMA GEMM, BK=64
// R0-proven loop structure restored (R1's dbuf global_load_lds + counted
// vmcnt regressed 187->205: these shapes are latency/occupancy-bound, and
// the reg-staged T14-style pipeline + 6 blocks/CU already hides latency;
// doubling LDS for a 2-deep DMA pipeline bought nothing and cost occupancy).
// LDS [row][72]: 2-way bank max (free, m136). Single buffer.
// dtype probes (detect1) run AFTER the K-loop so they never delay staging.
// EPI: 0 = +bias -> bf16            1 = gelu(+bias) -> bf16
//      2 = y[off] = v+bias+res      3 = y[off] += v (+bias if addb)
//      4 = out[off] = y[off] + v (+bias if addb; out dtype per probe)
template <int BM, int BN, int EPI>
__global__ __launch_bounds__(256)
void gemm_bt(const ushort_t* __restrict__ A, int lda,
             const ushort_t* __restrict__ BT, int ldb, int K,
             const void* __restrict__ bias, int bias_off, int bias_n,
             const void* __restrict__ res,
             const void* __restrict__ dprobe, int dprobe_n,
             float* __restrict__ yacc,
             ushort_t* __restrict__ out_bf, int ldo, int addb) {
  constexpr int BK = 64;
  constexpr int FM = BM / 32, FN = BN / 32;
  constexpr int AG = BM / 32, BG = BN / 32;   // staging groups of 32 rows
  __shared__ __attribute__((aligned(16))) ushort_t As[BM][72];
  __shared__ __attribute__((aligned(16))) ushort_t Bs[BN][72];

  const int t = threadIdx.x;
  const int lane = t & 63, wave = t >> 6;
  const int wm = wave >> 1, wn = wave & 1;
  const int q = lane >> 4, lm = lane & 15;
  const int m0 = blockIdx.y * BM, n0 = blockIdx.x * BN;
  const int srow = t >> 3, sslot = t & 7;   // 32 rows x 8 chunks per pass

  f32x4 acc[FM][FN];
#pragma unroll
  for (int i = 0; i < FM; ++i)
#pragma unroll
    for (int j = 0; j < FN; ++j) acc[i][j] = (f32x4)(0.0f);

  u16x8 av[AG], bv[BG];

  auto gload = [&](int k0) {
#pragma unroll
    for (int r = 0; r < AG; ++r)
      av[r] = *(const u16x8*)(A + (size_t)(m0 + r * 32 + srow) * lda + k0 + sslot * 8);
#pragma unroll
    for (int r = 0; r < BG; ++r)
      bv[r] = *(const u16x8*)(BT + (size_t)(n0 + r * 32 + srow) * ldb + k0 + sslot * 8);
  };
  auto swrite = [&]() {
#pragma unroll
    for (int r = 0; r < AG; ++r) *(u16x8*)&As[r * 32 + srow][sslot * 8] = av[r];
#pragma unroll
    for (int r = 0; r < BG; ++r) *(u16x8*)&Bs[r * 32 + srow][sslot * 8] = bv[r];
  };
  auto frag_mfma = [&](int kh) {
    s16x8 af[FM], bf[FN];
#pragma unroll
    for (int i = 0; i < FM; ++i)
      af[i] = *(const s16x8*)&As[wm * (BM / 2) + i * 16 + lm][kh * 32 + q * 8];
#pragma unroll
    for (int j = 0; j < FN; ++j)
      bf[j] = *(const s16x8*)&Bs[wn * (BN / 2) + j * 16 + lm][kh * 32 + q * 8];
#pragma unroll
    for (int i = 0; i < FM; ++i)
#pragma unroll
      for (int j = 0; j < FN; ++j)
        acc[i][j] = __builtin_amdgcn_mfma_f32_16x16x32_bf16(af[i], bf[j], acc[i][j], 0, 0, 0);
  };

  gload(0);
  swrite();
  __syncthreads();
  for (int k0 = BK; k0 < K; k0 += BK) {
    gload(k0);          // next tile in flight over current tile's MFMA
    frag_mfma(0);
    frag_mfma(1);
    __syncthreads();
    swrite();
    __syncthreads();
  }
  frag_mfma(0);
  frag_mfma(1);

  // dtype probes after the hot loop — never on the staging critical path
  const int fbias = detect1(bias, bias_n);
  int fres = 0;
  if constexpr (EPI == 2 || EPI == 4) fres = detect1(dprobe, dprobe_n);

#pragma unroll
  for (int i = 0; i < FM; ++i) {
#pragma unroll
    for (int j = 0; j < FN; ++j) {
      const int colg = n0 + wn * (BN / 2) + j * 16 + lm;
      float bb = 0.0f;
      if (EPI <= 2 || addb) bb = ldx(bias, bias_off + colg, fbias);
#pragma unroll
      for (int r = 0; r < 4; ++r) {
        const int rowg = m0 + wm * (BM / 2) + i * 16 + q * 4 + r;
        float v = acc[i][j][r] + bb;
        const size_t off = (size_t)rowg * ldo + colg;
        if constexpr (EPI == 0) {
          out_bf[off] = f2bf(v);
        } else if constexpr (EPI == 1) {
          out_bf[off] = f2bf(0.5f * v * (1.0f + erff(v * 0.70710678f)));
        } else if constexpr (EPI == 2) {
          yacc[off] = v + ldx(res, off, fres);
        } else if constexpr (EPI == 3) {
          yacc[off] += v;
        } else {
          float fin = yacc[off] + v;
          if (fres) ((float*)(void*)out_bf)[off] = fin;
          else      out_bf[off] = f2bf(fin);
        }
      }
    }
  }
}

// ------------------------------------------------- legacy GEMM (fallback path, r6-proven)
template <int BM, int BN, int EPI>
__global__ __launch_bounds__(256)
void gemm_nn(const ushort_t* __restrict__ A, int lda, int K,
             const void* __restrict__ B, int ldb, int brow0, int bcol0,
             const void* __restrict__ bias, int bias_off,
             const void* __restrict__ res,
             float* __restrict__ yacc,
             ushort_t* __restrict__ out_bf, int ldo,
             const int* __restrict__ flags, int iB, int ibias, int ires, int addb) {
  constexpr int BK = 32;
  constexpr int FM = BM / 32, FN = BN / 32;
  __shared__ __attribute__((aligned(16))) ushort_t As[BM][40];
  __shared__ ushort_t Bs[BK][BN + 2];
  const int t = threadIdx.x;
  const int lane = t & 63, wave = t >> 6;
  const int wm = wave >> 1, wn = wave & 1;
  const int m0 = blockIdx.y * BM, n0 = blockIdx.x * BN;
  const int fB = flags[iB], fbias = flags[ibias];
  f32x4 acc[FM][FN];
#pragma unroll
  for (int i = 0; i < FM; ++i)
#pragma unroll
    for (int j = 0; j < FN; ++j) acc[i][j] = (f32x4)(0.0f);
  const int q = lane >> 4, lm = lane & 15;
  const int arow_s = t >> 2, aslot = t & 3;
  for (int k0 = 0; k0 < K; k0 += BK) {
    __syncthreads();
#pragma unroll
    for (int r = 0; r < BM / 64; ++r) {
      int row = r * 64 + arow_s;
      *(u16x8*)&As[row][aslot * 8] =
          *(const u16x8*)(A + (size_t)(m0 + row) * lda + k0 + aslot * 8);
    }
#pragma unroll
    for (int e = 0; e < (BK * BN) / 256; ++e) {
      int id = e * 256 + t;
      int k = id / BN, n = id % BN;
      Bs[k][n] = f2bf(ldx(B, (size_t)(brow0 + k0 + k) * ldb + bcol0 + n0 + n, fB));
    }
    __syncthreads();
    s16x8 af[FM], bf[FN];
#pragma unroll
    for (int i = 0; i < FM; ++i)
      af[i] = *(const s16x8*)&As[wm * (BM / 2) + i * 16 + lm][q * 8];
#pragma unroll
    for (int j = 0; j < FN; ++j) {
      int nl = wn * (BN / 2) + j * 16 + lm;
      u16x8 tmp;
#pragma unroll
      for (int f = 0; f < 8; ++f) tmp[f] = Bs[q * 8 + f][nl];
      bf[j] = __builtin_bit_cast(s16x8, tmp);
    }
#pragma unroll
    for (int i = 0; i < FM; ++i)
#pragma unroll
      for (int j = 0; j < FN; ++j)
        acc[i][j] = __builtin_amdgcn_mfma_f32_16x16x32_bf16(af[i], bf[j], acc[i][j], 0, 0, 0);
  }
#pragma unroll
  for (int i = 0; i < FM; ++i) {
#pragma unroll
    for (int j = 0; j < FN; ++j) {
      const int col = wn * (BN / 2) + j * 16 + lm;
      float bb = 0.0f;
      if (EPI != 3 || addb) bb = ldx(bias, bias_off + n0 + col, fbias);
#pragma unroll
      for (int r = 0; r < 4; ++r) {
        const int rowg = m0 + wm * (BM / 2) + i * 16 + q * 4 + r;
        float v = acc[i][j][r] + bb;
        if constexpr (EPI == 0) {
          out_bf[(size_t)rowg * ldo + n0 + col] = f2bf(v);
        } else if constexpr (EPI == 1) {
          out_bf[(size_t)rowg * ldo + n0 + col] =
              f2bf(0.5f * v * (1.0f + erff(v * 0.70710678f)));
        } else if constexpr (EPI == 2) {
          const size_t off = (size_t)rowg * D_MODEL + n0 + col;
          yacc[off] = v + ldx(res, off, flags[ires]);
        } else {
          const size_t off = (size_t)rowg * D_MODEL + n0 + col;
          yacc[off] += v;
        }
      }
    }
  }
}

// ------------------------------------------------- attention (r14 coalesced-K)
__device__ __forceinline__ int key_index(int s, int j, int S) {
  int p;
  if (j < 64)       p = s + j - 32;
  else if (j < 102) p = s + (j - 83) * 64;
  else              p = ((j - 102) * (S - 1)) / 25;
  return min(max(p, 0), S - 1);
}

__global__ __launch_bounds__(256, 4)
void attn_kernel(const ushort_t* __restrict__ qkv, ushort_t* __restrict__ out, int S) {
  const int wave = threadIdx.x >> 6, lane = threadIdx.x & 63;
  const int pair = blockIdx.x * 4 + wave;   // pair = h*S + s
  const int h = pair / S;
  const int s = pair - h * S;
  const int g = lane >> 3, d8 = (lane & 7) * 8;

  int koff[16];
#pragma unroll
  for (int r = 0; r < 16; ++r)
    koff[r] = key_index(s, r * 8 + g, S) * (3 * D_MODEL);

  u16x8 qv8 = *(const u16x8*)(qkv + (size_t)s * (3 * D_MODEL) + h * HEAD_D + d8);
  float qf[8];
#pragma unroll
  for (int e = 0; e < 8; ++e) qf[e] = bf2f(qv8[e]);

  const ushort_t* kbase = qkv + D_MODEL + h * HEAD_D + d8;
  float pr[16];
  {
    u16x8 kv[8];
#pragma unroll
    for (int r = 0; r < 8; ++r) kv[r] = *(const u16x8*)(kbase + koff[r]);
#pragma unroll
    for (int r = 0; r < 16; ++r) {
      u16x8 cur = kv[r & 7];
      if (r < 8) kv[r & 7] = *(const u16x8*)(kbase + koff[r + 8]);
      float d = 0.f;
#pragma unroll
      for (int e = 0; e < 8; ++e) d += qf[e] * bf2f(cur[e]);
      d += __shfl_xor(d, 1);
      d += __shfl_xor(d, 2);
      d += __shfl_xor(d, 4);
      pr[r] = d * 0.125f;
    }
  }

  float mx = pr[0];
#pragma unroll
  for (int r = 1; r < 16; ++r) mx = fmaxf(mx, pr[r]);
#pragma unroll
  for (int m = 8; m <= 32; m <<= 1) mx = fmaxf(mx, __shfl_xor(mx, m));
  float sm = 0.f;
#pragma unroll
  for (int r = 0; r < 16; ++r) { pr[r] = __expf(pr[r] - mx); sm += pr[r]; }
#pragma unroll
  for (int m = 8; m <= 32; m <<= 1) sm += __shfl_xor(sm, m);
  const float inv = 1.0f / sm;

  const ushort_t* vbase = qkv + 2 * D_MODEL + h * HEAD_D + d8;
  float oacc[8];
#pragma unroll
  for (int e = 0; e < 8; ++e) oacc[e] = 0.f;
  {
    u16x8 vv[8];
#pragma unroll
    for (int r = 0; r < 8; ++r) vv[r] = *(const u16x8*)(vbase + koff[r]);
#pragma unroll
    for (int r = 0; r < 16; ++r) {
      u16x8 cv = vv[r & 7];
      float cp = pr[r] * inv;
      if (r < 8) vv[r & 7] = *(const u16x8*)(vbase + koff[r + 8]);
#pragma unroll
      for (int e = 0; e < 8; ++e) oacc[e] += cp * bf2f(cv[e]);
    }
  }
#pragma unroll
  for (int m = 8; m <= 32; m <<= 1)
#pragma unroll
    for (int e = 0; e < 8; ++e) oacc[e] += __shfl_xor(oacc[e], m);

  if (lane < 8) {
    u16x8 ov;
#pragma unroll
    for (int e = 0; e < 8; ++e) ov[e] = f2bf(oacc[e]);
    *(u16x8*)(out + (size_t)s * D_MODEL + h * HEAD_D + d8) = ov;
  }
}

// ------------------------------------------------- final convert (fallback only)
__global__ __launch_bounds__(256)
void convert_kernel(const float* __restrict__ y, void* __restrict__ out,
                    const int* __restrict__ flags, int n) {
  const int fout = flags[0];
  int i = blockIdx.x * 256 + threadIdx.x;
  if (i < n) {
    float v = y[i];
    if (fout) ((float*)out)[i] = v;
    else      ((ushort_t*)out)[i] = f2bf(v);
  }
}

// ------------------------------------------------- launch
extern "C" void kernel_launch(void* const* d_in, const int* in_sizes, int n_in,
                              void* d_out, int out_size, void* d_ws, size_t ws_size,
                              hipStream_t stream) {
  const int S = in_sizes[0] / D_MODEL;    // 2048
  const size_t sD = (size_t)S * D_MODEL;
  char* ws = (char*)d_ws;

  ushort_t* h1    = (ushort_t*)d_out;
  ushort_t* attnb = (ushort_t*)d_out;
  ushort_t* h2    = (ushort_t*)d_out;

  const size_t MB = 1024 * 1024;
  if (ws_size >= 12 * MB + 64) {
    const int P  = (ws_size >= 20 * MB) ? 1 : 2;
    const int Nc = D_FFN / P;
    char* wbase = ws + (P == 1 ? 12 : 6) * MB;

    ushort_t* qkv   = (ushort_t*)ws;                       // [0,6M)
    float*    y     = (float*)ws;                          // [0,4M) after qkv dies
    ushort_t* gbuf  = (ushort_t*)(ws + 4 * MB);            // S*Nc bf16 (4 or 8 MB)
    ushort_t* wqkvT = (ushort_t*)wbase;                    // 1.5 MB
    ushort_t* woT   = (ushort_t*)(wbase + 1 * MB + 512 * 1024);  // 0.5 MB
    ushort_t* w1T   = (ushort_t*)(wbase + 2 * MB);         // 2 MB
    ushort_t* w2T   = (ushort_t*)(wbase + 4 * MB);         // 2 MB

    WDesc dq  = { d_in[6],  wqkvT, D_MODEL, 3 * D_MODEL, D_MODEL * 3 * D_MODEL, 0 };
    WDesc dwo = { d_in[8],  woT,   D_MODEL, D_MODEL,     D_MODEL * D_MODEL,     768 };
    WDesc dw1 = { d_in[10], w1T,   D_MODEL, D_FFN,       D_MODEL * D_FFN,       1024 };
    WDesc dw2 = { d_in[12], w2T,   D_FFN,   D_MODEL,     D_FFN * D_MODEL,       2048 };

    // K1: weight convert (3072 blocks) + ln1 (S/4 blocks) in ONE launch
    prep_kernel<<<3072 + S / 4, 256, 0, stream>>>(
        dq, dwo, dw1, dw2, 3072, d_in[0], d_in[2], d_in[3], h1, (int)sD);

    // GEMM1: h1 @ wqkv + bqkv -> qkv  (32x64, 1536 blocks, 6/CU)
    gemm_bt<32, 64, 0><<<dim3(24, S / 32), 256, 0, stream>>>(
        h1, D_MODEL, wqkvT, D_MODEL, D_MODEL, d_in[7], 0, 3 * D_MODEL,
        nullptr, nullptr, 0, nullptr, qkv, 3 * D_MODEL, 1);

    attn_kernel<<<(S * N_HEADS) / 4, 256, 0, stream>>>(qkv, attnb, S);

    // GEMM2: attnb @ wo + bo + x -> y  (32x32, 1024 blocks, 4/CU)
    gemm_bt<32, 32, 2><<<dim3(16, S / 32), 256, 0, stream>>>(
        attnb, D_MODEL, woT, D_MODEL, D_MODEL, d_in[9], 0, D_MODEL,
        d_in[0], d_in[0], (int)sD, y, nullptr, D_MODEL, 1);

    ln2_kernel<<<S / 4, 256, 0, stream>>>(y, d_in[4], d_in[5], h2);

    if (P == 1) {
      // GEMM3: h2 @ w1 + b1 -> gelu -> gbuf  (32x64, 2048 blocks, 8/CU)
      gemm_bt<32, 64, 1><<<dim3(D_FFN / 64, S / 32), 256, 0, stream>>>(
          h2, D_MODEL, w1T, D_MODEL, D_MODEL,
          d_in[11], 0, D_FFN, nullptr, nullptr, 0, nullptr, gbuf, D_FFN, 1);
      // GEMM4: out = y + gbuf @ w2 + b2  (K=2048; 32x32, 1024 blocks, 4/CU)
      gemm_bt<32, 32, 4><<<dim3(16, S / 32), 256, 0, stream>>>(
          gbuf, D_FFN, w2T, D_FFN, D_FFN, d_in[13], 0, D_MODEL,
          nullptr, d_in[0], (int)sD, y, (ushort_t*)d_out, D_MODEL, 1);
    } else {
      gemm_bt<32, 64, 1><<<dim3(Nc / 64, S / 32), 256, 0, stream>>>(
          h2, D_MODEL, w1T, D_MODEL, D_MODEL,
          d_in[11], 0, D_FFN, nullptr, nullptr, 0, nullptr, gbuf, Nc, 1);
      gemm_bt<32, 32, 3><<<dim3(16, S / 32), 256, 0, stream>>>(
          gbuf, Nc, w2T, D_FFN, Nc, d_in[13], 0, D_MODEL,
          nullptr, nullptr, 0, y, nullptr, D_MODEL, 1);
      gemm_bt<32, 64, 1><<<dim3(Nc / 64, S / 32), 256, 0, stream>>>(
          h2, D_MODEL, w1T + (size_t)Nc * D_MODEL, D_MODEL, D_MODEL,
          d_in[11], Nc, D_FFN, nullptr, nullptr, 0, nullptr, gbuf, Nc, 1);
      gemm_bt<32, 32, 4><<<dim3(16, S / 32), 256, 0, stream>>>(
          gbuf, Nc, w2T + (size_t)Nc, D_FFN, Nc, d_in[13], 0, D_MODEL,
          nullptr, d_in[0], (int)sD, y, (ushort_t*)d_out, D_MODEL, 0);
    }
  } else {
    // fallback: round-6 proven path
    DetectArgs da;
    for (int i = 0; i < 14; ++i) { da.p[i] = d_in[i]; da.n[i] = in_sizes[i]; }
    int P;
    if      (ws_size >= 12ull * MB + 4096) P = 1;
    else if (ws_size >=  8ull * MB + 4096) P = 2;
    else                                   P = 4;
    const int Nc = D_FFN / P;
    const size_t gbuf_bytes = (size_t)S * Nc * 2;
    const size_t qkv_bytes  = 3 * sD * 2;
    const size_t fo = 4ull * sD + gbuf_bytes;
    const size_t flags_pos = (qkv_bytes > fo ? qkv_bytes : fo);

    ushort_t* qkv  = (ushort_t*)ws;
    float*    y    = (float*)ws;
    ushort_t* gbuf = (ushort_t*)(ws + 4 * sD);
    int*      flags = (int*)(ws + flags_pos);

    detect_all<<<14, 256, 0, stream>>>(da, flags);
    ln1_kernel<<<S / 4, 256, 0, stream>>>(d_in[0], d_in[2], d_in[3], h1, (int)sD);
    gemm_nn<128, 128, 0><<<dim3((3 * D_MODEL) / 128, S / 128), 256, 0, stream>>>(
        h1, D_MODEL, D_MODEL, d_in[6], 3 * D_MODEL, 0, 0, d_in[7], 0,
        nullptr, nullptr, qkv, 3 * D_MODEL, flags, 6, 7, 0, 1);
    attn_kernel<<<(S * N_HEADS) / 4, 256, 0, stream>>>(qkv, attnb, S);
    gemm_nn<64, 64, 2><<<dim3(D_MODEL / 64, S / 64), 256, 0, stream>>>(
        attnb, D_MODEL, D_MODEL, d_in[8], D_MODEL, 0, 0, d_in[9], 0,
        d_in[0], y, nullptr, D_MODEL, flags, 8, 9, 0, 1);
    ln2_kernel<<<S / 4, 256, 0, stream>>>(y, d_in[4], d_in[5], h2);
    for (int p = 0; p < P; ++p) {
      if (Nc >= 1024) {
        gemm_nn<128, 128, 1><<<dim3(Nc / 128, S / 128), 256, 0, stream>>>(
            h2, D_MODEL, D_MODEL, d_in[10], D_FFN, 0, p * Nc, d_in[11], p * Nc,
            nullptr, nullptr, gbuf, Nc, flags, 10, 11, 0, 1);
      } else {
        gemm_nn<64, 64, 1><<<dim3(Nc / 64, S / 64), 256, 0, stream>>>(
            h2, D_MODEL, D_MODEL, d_in[10], D_FFN, 0, p * Nc, d_in[11], p * Nc,
            nullptr, nullptr, gbuf, Nc, flags, 10, 11, 0, 1);
      }
      gemm_nn<64, 64, 3><<<dim3(D_MODEL / 64, S / 64), 256, 0, stream>>>(
          gbuf, Nc, Nc, d_in[12], D_MODEL, p * Nc, 0, d_in[13], 0,
          nullptr, y, nullptr, D_MODEL, flags, 12, 13, 0, p == 0 ? 1 : 0);
    }
    convert_kernel<<<(int)((sD + 255) / 256), 256, 0, stream>>>(y, d_out, flags, (int)sD);
  }
}

// Round 3
// 187.526 us; speedup vs baseline: 1.0936x; 1.0697x over previous
//
#include <hip/hip_runtime.h>
#include <math.h>

typedef float f32x4 __attribute__((ext_vector_type(4)));
typedef short s16x8 __attribute__((ext_vector_type(8)));
typedef unsigned short u16x8 __attribute__((ext_vector_type(8)));
typedef unsigned short ushort_t;
typedef unsigned int uint_t;

#define D_MODEL 512
#define N_HEADS 8
#define HEAD_D  64
#define D_FFN   2048

__device__ __forceinline__ float bf2f(unsigned short u) {
  union { unsigned int i; float f; } c; c.i = ((unsigned int)u) << 16; return c.f;
}
__device__ __forceinline__ unsigned short f2bf(float f) {
  union { float f; unsigned int i; } c; c.f = f;
  unsigned int x = c.i;
  return (unsigned short)((x + 0x7FFFu + ((x >> 16) & 1u)) >> 16);
}
__device__ __forceinline__ float ldx(const void* p, size_t i, int f) {
  return f ? ((const float*)p)[i] : bf2f(((const ushort_t*)p)[i]);
}

// ------------------------------------------------- fused dtype detector
// One tiny upfront kernel; every consumer pays a single scalar flags[] load.
// (R1/R2 lesson: inlining this probe per-block into consumer kernels costs
// ~13 µs of un-hidable tail latency across the chain — keep it amortized.)
struct DetectArgs { const void* p[14]; int n[14]; };

__global__ __launch_bounds__(256)
void detect_all(DetectArgs a, int* __restrict__ flags) {
  __shared__ int cnt[2];
  const int b = blockIdx.x;
  const int t = threadIdx.x;
  if (b == 1) { if (t == 0) flags[1] = 0; return; }
  if (t == 0) { cnt[0] = 0; cnt[1] = 0; }
  __syncthreads();
  const int n_u32 = a.n[b] >> 1;
  const int sample = n_u32 < 256 ? n_u32 : 256;
  if (t < sample) {
    uint_t u = ((const uint_t*)a.p[b])[t];
    if (u != 0u) {
      atomicAdd(&cnt[0], 1);
      int e = (u >> 7) & 0xFF;
      if (e >= 0x70 && e <= 0x83) atomicAdd(&cnt[1], 1);
    }
  }
  __syncthreads();
  if (t == 0) flags[b] = (cnt[0] >= 32 && cnt[1] * 4 <= cnt[0]) ? 1 : 0;
}

// ------------------------------------------------- prep: weight convert+transpose AND ln1
// Independent work merged into one launch (flags-based: no per-block probes).
struct WDesc { const void* src; ushort_t* dst; int Kd, Nd, flag, tile0; };

__global__ __launch_bounds__(256)
void prep_kernel(WDesc w0, WDesc w1, WDesc w2, WDesc w3, int nconv,
                 const void* __restrict__ x, const void* __restrict__ g,
                 const void* __restrict__ b, ushort_t* __restrict__ h1,
                 const int* __restrict__ flags) {
  __shared__ ushort_t tile[32][33];
  const int blk = blockIdx.x;
  if (blk >= nconv) {
    // ----- ln1 path (4 rows per block)
    const int fx = flags[0], fg = flags[2], fb = flags[3];
    const int row = (blk - nconv) * 4 + (threadIdx.x >> 6);
    const int lane = threadIdx.x & 63;
    float v[8], sum = 0.f, sq = 0.f;
#pragma unroll
    for (int i = 0; i < 8; ++i) {
      v[i] = ldx(x, (size_t)row * D_MODEL + lane * 8 + i, fx);
      sum += v[i]; sq += v[i] * v[i];
    }
#pragma unroll
    for (int o = 32; o > 0; o >>= 1) { sum += __shfl_xor(sum, o); sq += __shfl_xor(sq, o); }
    const float mu = sum * (1.0f / D_MODEL);
    const float var = sq * (1.0f / D_MODEL) - mu * mu;
    const float rstd = rsqrtf(var + 1e-5f);
#pragma unroll
    for (int i = 0; i < 8; ++i) {
      int c = lane * 8 + i;
      h1[(size_t)row * D_MODEL + c] =
          f2bf((v[i] - mu) * rstd * ldx(g, c, fg) + ldx(b, c, fb));
    }
    return;
  }
  // ----- weight convert+transpose path
  WDesc d = (blk < w1.tile0) ? w0 : (blk < w2.tile0) ? w1 : (blk < w3.tile0) ? w2 : w3;
  const int lt = blk - d.tile0;
  const int tn = d.Nd / 32;
  const int bk = lt / tn, bn = lt % tn;
  const int f = flags[d.flag];
  const int tx = threadIdx.x & 31, ty = threadIdx.x >> 5;
#pragma unroll
  for (int r = 0; r < 4; ++r) {
    int k = bk * 32 + ty * 4 + r;
    tile[ty * 4 + r][tx] = f2bf(ldx(d.src, (size_t)k * d.Nd + bn * 32 + tx, f));
  }
  __syncthreads();
#pragma unroll
  for (int r = 0; r < 4; ++r) {
    int n = bn * 32 + ty * 4 + r;
    d.dst[(size_t)n * d.Kd + bk * 32 + tx] = tile[tx][ty * 4 + r];
  }
}

// ------------------------------------------------- LN kernels
__global__ __launch_bounds__(256)
void ln1_kernel(const void* __restrict__ x, const void* __restrict__ g,
                const void* __restrict__ b, ushort_t* __restrict__ out,
                const int* __restrict__ flags) {
  const int fx = flags[0], fg = flags[2], fb = flags[3];
  const int row = blockIdx.x * 4 + (threadIdx.x >> 6);
  const int lane = threadIdx.x & 63;
  float v[8], sum = 0.f, sq = 0.f;
#pragma unroll
  for (int i = 0; i < 8; ++i) {
    v[i] = ldx(x, (size_t)row * D_MODEL + lane * 8 + i, fx);
    sum += v[i]; sq += v[i] * v[i];
  }
#pragma unroll
  for (int o = 32; o > 0; o >>= 1) { sum += __shfl_xor(sum, o); sq += __shfl_xor(sq, o); }
  const float mu = sum * (1.0f / D_MODEL);
  const float var = sq * (1.0f / D_MODEL) - mu * mu;
  const float rstd = rsqrtf(var + 1e-5f);
#pragma unroll
  for (int i = 0; i < 8; ++i) {
    int c = lane * 8 + i;
    out[(size_t)row * D_MODEL + c] =
        f2bf((v[i] - mu) * rstd * ldx(g, c, fg) + ldx(b, c, fb));
  }
}

__global__ __launch_bounds__(256)
void ln2_kernel(const float* __restrict__ y, const void* __restrict__ g,
                const void* __restrict__ b, ushort_t* __restrict__ out,
                const int* __restrict__ flags) {
  const int fg = flags[4], fb = flags[5];
  const int row = blockIdx.x * 4 + (threadIdx.x >> 6);
  const int lane = threadIdx.x & 63;
  float v[8], sum = 0.f, sq = 0.f;
#pragma unroll
  for (int i = 0; i < 8; ++i) {
    v[i] = y[(size_t)row * D_MODEL + lane * 8 + i];
    sum += v[i]; sq += v[i] * v[i];
  }
#pragma unroll
  for (int o = 32; o > 0; o >>= 1) { sum += __shfl_xor(sum, o); sq += __shfl_xor(sq, o); }
  const float mu = sum * (1.0f / D_MODEL);
  const float var = sq * (1.0f / D_MODEL) - mu * mu;
  const float rstd = rsqrtf(var + 1e-5f);
#pragma unroll
  for (int i = 0; i < 8; ++i) {
    int c = lane * 8 + i;
    out[(size_t)row * D_MODEL + c] =
        f2bf((v[i] - mu) * rstd * ldx(g, c, fg) + ldx(b, c, fb));
  }
}

// ------------------------------------------------- pipelined MFMA GEMM, BK=64
// R0-proven structure, untouched: single-buffer reg-staged pipeline, small
// tiles, [72] padding (2-way bank max, free per m136). Occupancy beats
// per-stage amortization for these latency-bound shapes (r13/r16, R1 lesson).
// EPI: 0 = +bias -> bf16            1 = gelu(+bias) -> bf16
//      2 = y[off] = v+bias+res      3 = y[off] += v (+bias if addb)
//      4 = out[off] = y[off] + v (+bias if addb; dtype per flags[ires])
template <int BM, int BN, int EPI>
__global__ __launch_bounds__(256)
void gemm_bt(const ushort_t* __restrict__ A, int lda,
             const ushort_t* __restrict__ BT, int ldb, int K,
             const void* __restrict__ bias, int bias_off,
             const void* __restrict__ res,
             float* __restrict__ yacc,
             ushort_t* __restrict__ out_bf, int ldo,
             const int* __restrict__ flags, int ibias, int ires, int addb) {
  constexpr int BK = 64;
  constexpr int FM = BM / 32, FN = BN / 32;
  constexpr int AG = BM / 32, BG = BN / 32;   // staging groups of 32 rows
  __shared__ __attribute__((aligned(16))) ushort_t As[BM][72];
  __shared__ __attribute__((aligned(16))) ushort_t Bs[BN][72];

  const int t = threadIdx.x;
  const int lane = t & 63, wave = t >> 6;
  const int wm = wave >> 1, wn = wave & 1;
  const int q = lane >> 4, lm = lane & 15;
  const int m0 = blockIdx.y * BM, n0 = blockIdx.x * BN;
  const int srow = t >> 3, sslot = t & 7;   // 32 rows x 8 chunks per pass

  f32x4 acc[FM][FN];
#pragma unroll
  for (int i = 0; i < FM; ++i)
#pragma unroll
    for (int j = 0; j < FN; ++j) acc[i][j] = (f32x4)(0.0f);

  u16x8 av[AG], bv[BG];

  auto gload = [&](int k0) {
#pragma unroll
    for (int r = 0; r < AG; ++r)
      av[r] = *(const u16x8*)(A + (size_t)(m0 + r * 32 + srow) * lda + k0 + sslot * 8);
#pragma unroll
    for (int r = 0; r < BG; ++r)
      bv[r] = *(const u16x8*)(BT + (size_t)(n0 + r * 32 + srow) * ldb + k0 + sslot * 8);
  };
  auto swrite = [&]() {
#pragma unroll
    for (int r = 0; r < AG; ++r) *(u16x8*)&As[r * 32 + srow][sslot * 8] = av[r];
#pragma unroll
    for (int r = 0; r < BG; ++r) *(u16x8*)&Bs[r * 32 + srow][sslot * 8] = bv[r];
  };
  auto frag_mfma = [&](int kh) {
    s16x8 af[FM], bf[FN];
#pragma unroll
    for (int i = 0; i < FM; ++i)
      af[i] = *(const s16x8*)&As[wm * (BM / 2) + i * 16 + lm][kh * 32 + q * 8];
#pragma unroll
    for (int j = 0; j < FN; ++j)
      bf[j] = *(const s16x8*)&Bs[wn * (BN / 2) + j * 16 + lm][kh * 32 + q * 8];
#pragma unroll
    for (int i = 0; i < FM; ++i)
#pragma unroll
      for (int j = 0; j < FN; ++j)
        acc[i][j] = __builtin_amdgcn_mfma_f32_16x16x32_bf16(af[i], bf[j], acc[i][j], 0, 0, 0);
  };

  gload(0);
  swrite();
  __syncthreads();
  for (int k0 = BK; k0 < K; k0 += BK) {
    gload(k0);          // next tile in flight over current tile's MFMA
    frag_mfma(0);
    frag_mfma(1);
    __syncthreads();
    swrite();
    __syncthreads();
  }
  frag_mfma(0);
  frag_mfma(1);

  const int fbias = flags[ibias];
#pragma unroll
  for (int i = 0; i < FM; ++i) {
#pragma unroll
    for (int j = 0; j < FN; ++j) {
      const int colg = n0 + wn * (BN / 2) + j * 16 + lm;
      float bb = 0.0f;
      if (EPI <= 2 || addb) bb = ldx(bias, bias_off + colg, fbias);
#pragma unroll
      for (int r = 0; r < 4; ++r) {
        const int rowg = m0 + wm * (BM / 2) + i * 16 + q * 4 + r;
        float v = acc[i][j][r] + bb;
        const size_t off = (size_t)rowg * ldo + colg;
        if constexpr (EPI == 0) {
          out_bf[off] = f2bf(v);
        } else if constexpr (EPI == 1) {
          out_bf[off] = f2bf(0.5f * v * (1.0f + erff(v * 0.70710678f)));
        } else if constexpr (EPI == 2) {
          yacc[off] = v + ldx(res, off, flags[ires]);
        } else if constexpr (EPI == 3) {
          yacc[off] += v;
        } else {
          float fin = yacc[off] + v;
          if (flags[ires]) ((float*)(void*)out_bf)[off] = fin;
          else             out_bf[off] = f2bf(fin);
        }
      }
    }
  }
}

// ------------------------------------------------- legacy GEMM (fallback path, r6-proven)
template <int BM, int BN, int EPI>
__global__ __launch_bounds__(256)
void gemm_nn(const ushort_t* __restrict__ A, int lda, int K,
             const void* __restrict__ B, int ldb, int brow0, int bcol0,
             const void* __restrict__ bias, int bias_off,
             const void* __restrict__ res,
             float* __restrict__ yacc,
             ushort_t* __restrict__ out_bf, int ldo,
             const int* __restrict__ flags, int iB, int ibias, int ires, int addb) {
  constexpr int BK = 32;
  constexpr int FM = BM / 32, FN = BN / 32;
  __shared__ __attribute__((aligned(16))) ushort_t As[BM][40];
  __shared__ ushort_t Bs[BK][BN + 2];
  const int t = threadIdx.x;
  const int lane = t & 63, wave = t >> 6;
  const int wm = wave >> 1, wn = wave & 1;
  const int m0 = blockIdx.y * BM, n0 = blockIdx.x * BN;
  const int fB = flags[iB], fbias = flags[ibias];
  f32x4 acc[FM][FN];
#pragma unroll
  for (int i = 0; i < FM; ++i)
#pragma unroll
    for (int j = 0; j < FN; ++j) acc[i][j] = (f32x4)(0.0f);
  const int q = lane >> 4, lm = lane & 15;
  const int arow_s = t >> 2, aslot = t & 3;
  for (int k0 = 0; k0 < K; k0 += BK) {
    __syncthreads();
#pragma unroll
    for (int r = 0; r < BM / 64; ++r) {
      int row = r * 64 + arow_s;
      *(u16x8*)&As[row][aslot * 8] =
          *(const u16x8*)(A + (size_t)(m0 + row) * lda + k0 + aslot * 8);
    }
#pragma unroll
    for (int e = 0; e < (BK * BN) / 256; ++e) {
      int id = e * 256 + t;
      int k = id / BN, n = id % BN;
      Bs[k][n] = f2bf(ldx(B, (size_t)(brow0 + k0 + k) * ldb + bcol0 + n0 + n, fB));
    }
    __syncthreads();
    s16x8 af[FM], bf[FN];
#pragma unroll
    for (int i = 0; i < FM; ++i)
      af[i] = *(const s16x8*)&As[wm * (BM / 2) + i * 16 + lm][q * 8];
#pragma unroll
    for (int j = 0; j < FN; ++j) {
      int nl = wn * (BN / 2) + j * 16 + lm;
      u16x8 tmp;
#pragma unroll
      for (int f = 0; f < 8; ++f) tmp[f] = Bs[q * 8 + f][nl];
      bf[j] = __builtin_bit_cast(s16x8, tmp);
    }
#pragma unroll
    for (int i = 0; i < FM; ++i)
#pragma unroll
      for (int j = 0; j < FN; ++j)
        acc[i][j] = __builtin_amdgcn_mfma_f32_16x16x32_bf16(af[i], bf[j], acc[i][j], 0, 0, 0);
  }
#pragma unroll
  for (int i = 0; i < FM; ++i) {
#pragma unroll
    for (int j = 0; j < FN; ++j) {
      const int col = wn * (BN / 2) + j * 16 + lm;
      float bb = 0.0f;
      if (EPI != 3 || addb) bb = ldx(bias, bias_off + n0 + col, fbias);
#pragma unroll
      for (int r = 0; r < 4; ++r) {
        const int rowg = m0 + wm * (BM / 2) + i * 16 + q * 4 + r;
        float v = acc[i][j][r] + bb;
        if constexpr (EPI == 0) {
          out_bf[(size_t)rowg * ldo + n0 + col] = f2bf(v);
        } else if constexpr (EPI == 1) {
          out_bf[(size_t)rowg * ldo + n0 + col] =
              f2bf(0.5f * v * (1.0f + erff(v * 0.70710678f)));
        } else if constexpr (EPI == 2) {
          const size_t off = (size_t)rowg * D_MODEL + n0 + col;
          yacc[off] = v + ldx(res, off, flags[ires]);
        } else {
          const size_t off = (size_t)rowg * D_MODEL + n0 + col;
          yacc[off] += v;
        }
      }
    }
  }
}

// ------------------------------------------------- attention (r14 coalesced-K)
// NEW: XCD-aware block swizzle (T1). Consecutive default blockIdx round-robin
// across 8 XCDs, so the heavily-overlapping K/V windows of neighboring s get
// replicated into 8 private L2s from L3 every iteration (qkv is rewritten by
// gemm1 each time -> cold refetch). The bijection below gives each XCD a
// contiguous pair range (for S=2048: exactly one head, 512 KB K+V slice that
// then lives in that XCD's L2 for all 2048 queries).
__device__ __forceinline__ int key_index(int s, int j, int S) {
  int p;
  if (j < 64)       p = s + j - 32;
  else if (j < 102) p = s + (j - 83) * 64;
  else              p = ((j - 102) * (S - 1)) / 25;
  return min(max(p, 0), S - 1);
}

__global__ __launch_bounds__(256, 4)
void attn_kernel(const ushort_t* __restrict__ qkv, ushort_t* __restrict__ out, int S) {
  const int wave = threadIdx.x >> 6, lane = threadIdx.x & 63;
  const int nb = gridDim.x;
  int bid = blockIdx.x;
  if ((nb & 7) == 0) bid = (bid & 7) * (nb >> 3) + (bid >> 3);  // XCD swizzle (bijective)
  const int pair = bid * 4 + wave;          // pair = h*S + s
  const int h = pair / S;
  const int s = pair - h * S;
  const int g = lane >> 3, d8 = (lane & 7) * 8;

  int koff[16];
#pragma unroll
  for (int r = 0; r < 16; ++r)
    koff[r] = key_index(s, r * 8 + g, S) * (3 * D_MODEL);

  u16x8 qv8 = *(const u16x8*)(qkv + (size_t)s * (3 * D_MODEL) + h * HEAD_D + d8);
  float qf[8];
#pragma unroll
  for (int e = 0; e < 8; ++e) qf[e] = bf2f(qv8[e]);

  const ushort_t* kbase = qkv + D_MODEL + h * HEAD_D + d8;
  float pr[16];
  {
    u16x8 kv[8];
#pragma unroll
    for (int r = 0; r < 8; ++r) kv[r] = *(const u16x8*)(kbase + koff[r]);
#pragma unroll
    for (int r = 0; r < 16; ++r) {
      u16x8 cur = kv[r & 7];
      if (r < 8) kv[r & 7] = *(const u16x8*)(kbase + koff[r + 8]);
      float d = 0.f;
#pragma unroll
      for (int e = 0; e < 8; ++e) d += qf[e] * bf2f(cur[e]);
      d += __shfl_xor(d, 1);
      d += __shfl_xor(d, 2);
      d += __shfl_xor(d, 4);
      pr[r] = d * 0.125f;
    }
  }

  float mx = pr[0];
#pragma unroll
  for (int r = 1; r < 16; ++r) mx = fmaxf(mx, pr[r]);
#pragma unroll
  for (int m = 8; m <= 32; m <<= 1) mx = fmaxf(mx, __shfl_xor(mx, m));
  float sm = 0.f;
#pragma unroll
  for (int r = 0; r < 16; ++r) { pr[r] = __expf(pr[r] - mx); sm += pr[r]; }
#pragma unroll
  for (int m = 8; m <= 32; m <<= 1) sm += __shfl_xor(sm, m);
  const float inv = 1.0f / sm;

  const ushort_t* vbase = qkv + 2 * D_MODEL + h * HEAD_D + d8;
  float oacc[8];
#pragma unroll
  for (int e = 0; e < 8; ++e) oacc[e] = 0.f;
  {
    u16x8 vv[8];
#pragma unroll
    for (int r = 0; r < 8; ++r) vv[r] = *(const u16x8*)(vbase + koff[r]);
#pragma unroll
    for (int r = 0; r < 16; ++r) {
      u16x8 cv = vv[r & 7];
      float cp = pr[r] * inv;
      if (r < 8) vv[r & 7] = *(const u16x8*)(vbase + koff[r + 8]);
#pragma unroll
      for (int e = 0; e < 8; ++e) oacc[e] += cp * bf2f(cv[e]);
    }
  }
#pragma unroll
  for (int m = 8; m <= 32; m <<= 1)
#pragma unroll
    for (int e = 0; e < 8; ++e) oacc[e] += __shfl_xor(oacc[e], m);

  if (lane < 8) {
    u16x8 ov;
#pragma unroll
    for (int e = 0; e < 8; ++e) ov[e] = f2bf(oacc[e]);
    *(u16x8*)(out + (size_t)s * D_MODEL + h * HEAD_D + d8) = ov;
  }
}

// ------------------------------------------------- final convert (fallback only)
__global__ __launch_bounds__(256)
void convert_kernel(const float* __restrict__ y, void* __restrict__ out,
                    const int* __restrict__ flags, int n) {
  const int fout = flags[0];
  int i = blockIdx.x * 256 + threadIdx.x;
  if (i < n) {
    float v = y[i];
    if (fout) ((float*)out)[i] = v;
    else      ((ushort_t*)out)[i] = f2bf(v);
  }
}

// ------------------------------------------------- launch
extern "C" void kernel_launch(void* const* d_in, const int* in_sizes, int n_in,
                              void* d_out, int out_size, void* d_ws, size_t ws_size,
                              hipStream_t stream) {
  const int S = in_sizes[0] / D_MODEL;    // 2048
  const size_t sD = (size_t)S * D_MODEL;
  char* ws = (char*)d_ws;

  DetectArgs da;
  for (int i = 0; i < 14; ++i) { da.p[i] = d_in[i]; da.n[i] = in_sizes[i]; }

  ushort_t* h1    = (ushort_t*)d_out;
  ushort_t* attnb = (ushort_t*)d_out;
  ushort_t* h2    = (ushort_t*)d_out;

  const size_t MB = 1024 * 1024;
  if (ws_size >= 12 * MB + 64) {
    const int P  = (ws_size >= 20 * MB) ? 1 : 2;
    const int Nc = D_FFN / P;
    char* wbase = ws + (P == 1 ? 12 : 6) * MB;

    ushort_t* qkv   = (ushort_t*)ws;                       // [0,6M)
    float*    y     = (float*)ws;                          // [0,4M) after qkv dies
    ushort_t* gbuf  = (ushort_t*)(ws + 4 * MB);            // S*Nc bf16 (4 or 8 MB)
    ushort_t* wqkvT = (ushort_t*)wbase;                    // 1.5 MB
    ushort_t* woT   = (ushort_t*)(wbase + 1 * MB + 512 * 1024);  // 0.5 MB
    ushort_t* w1T   = (ushort_t*)(wbase + 2 * MB);         // 2 MB
    ushort_t* w2T   = (ushort_t*)(wbase + 4 * MB);         // 2 MB
    int*      flags = (int*)(wbase + 6 * MB);

    detect_all<<<14, 256, 0, stream>>>(da, flags);

    WDesc dq  = { d_in[6],  wqkvT, D_MODEL, 3 * D_MODEL, 6,  0 };
    WDesc dwo = { d_in[8],  woT,   D_MODEL, D_MODEL,     8,  768 };
    WDesc dw1 = { d_in[10], w1T,   D_MODEL, D_FFN,       10, 1024 };
    WDesc dw2 = { d_in[12], w2T,   D_FFN,   D_MODEL,     12, 2048 };

    // K2: weight convert (3072 blocks) + ln1 (S/4 blocks), flags-based
    prep_kernel<<<3072 + S / 4, 256, 0, stream>>>(
        dq, dwo, dw1, dw2, 3072, d_in[0], d_in[2], d_in[3], h1, flags);

    // GEMM1: h1 @ wqkv + bqkv -> qkv  (32x64, 1536 blocks, 6/CU)
    gemm_bt<32, 64, 0><<<dim3(24, S / 32), 256, 0, stream>>>(
        h1, D_MODEL, wqkvT, D_MODEL, D_MODEL, d_in[7], 0,
        nullptr, nullptr, qkv, 3 * D_MODEL, flags, 7, 0, 1);

    attn_kernel<<<(S * N_HEADS) / 4, 256, 0, stream>>>(qkv, attnb, S);

    // GEMM2: attnb @ wo + bo + x -> y (32x32, 1024 blocks, 4/CU)
    gemm_bt<32, 32, 2><<<dim3(16, S / 32), 256, 0, stream>>>(
        attnb, D_MODEL, woT, D_MODEL, D_MODEL, d_in[9], 0,
        d_in[0], y, nullptr, D_MODEL, flags, 9, 0, 1);

    ln2_kernel<<<S / 4, 256, 0, stream>>>(y, d_in[4], d_in[5], h2, flags);

    if (P == 1) {
      // GEMM3: h2 @ w1 + b1 -> gelu -> gbuf  (32x64, 2048 blocks, 8/CU)
      gemm_bt<32, 64, 1><<<dim3(D_FFN / 64, S / 32), 256, 0, stream>>>(
          h2, D_MODEL, w1T, D_MODEL, D_MODEL,
          d_in[11], 0, nullptr, nullptr, gbuf, D_FFN, flags, 11, 0, 1);
      // GEMM4: out = y + gbuf @ w2 + b2  (K=2048; 32x32, 1024 blocks, 4/CU)
      gemm_bt<32, 32, 4><<<dim3(16, S / 32), 256, 0, stream>>>(
          gbuf, D_FFN, w2T, D_FFN, D_FFN, d_in[13], 0,
          nullptr, y, (ushort_t*)d_out, D_MODEL, flags, 13, 0, 1);
    } else {
      gemm_bt<32, 64, 1><<<dim3(Nc / 64, S / 32), 256, 0, stream>>>(
          h2, D_MODEL, w1T, D_MODEL, D_MODEL,
          d_in[11], 0, nullptr, nullptr, gbuf, Nc, flags, 11, 0, 1);
      gemm_bt<32, 32, 3><<<dim3(16, S / 32), 256, 0, stream>>>(
          gbuf, Nc, w2T, D_FFN, Nc, d_in[13], 0,
          nullptr, y, nullptr, D_MODEL, flags, 13, 0, 1);
      gemm_bt<32, 64, 1><<<dim3(Nc / 64, S / 32), 256, 0, stream>>>(
          h2, D_MODEL, w1T + (size_t)Nc * D_MODEL, D_MODEL, D_MODEL,
          d_in[11], Nc, nullptr, nullptr, gbuf, Nc, flags, 11, 0, 1);
      gemm_bt<32, 32, 4><<<dim3(16, S / 32), 256, 0, stream>>>(
          gbuf, Nc, w2T + (size_t)Nc, D_FFN, Nc, d_in[13], 0,
          nullptr, y, (ushort_t*)d_out, D_MODEL, flags, 13, 0, 0);
    }
  } else {
    // fallback: round-6 proven path
    int P;
    if      (ws_size >= 12ull * MB + 4096) P = 1;
    else if (ws_size >=  8ull * MB + 4096) P = 2;
    else                                   P = 4;
    const int Nc = D_FFN / P;
    const size_t gbuf_bytes = (size_t)S * Nc * 2;
    const size_t qkv_bytes  = 3 * sD * 2;
    const size_t fo = 4ull * sD + gbuf_bytes;
    const size_t flags_pos = (qkv_bytes > fo ? qkv_bytes : fo);

    ushort_t* qkv  = (ushort_t*)ws;
    float*    y    = (float*)ws;
    ushort_t* gbuf = (ushort_t*)(ws + 4 * sD);
    int*      flags = (int*)(ws + flags_pos);

    detect_all<<<14, 256, 0, stream>>>(da, flags);
    ln1_kernel<<<S / 4, 256, 0, stream>>>(d_in[0], d_in[2], d_in[3], h1, flags);
    gemm_nn<128, 128, 0><<<dim3((3 * D_MODEL) / 128, S / 128), 256, 0, stream>>>(
        h1, D_MODEL, D_MODEL, d_in[6], 3 * D_MODEL, 0, 0, d_in[7], 0,
        nullptr, nullptr, qkv, 3 * D_MODEL, flags, 6, 7, 0, 1);
    attn_kernel<<<(S * N_HEADS) / 4, 256, 0, stream>>>(qkv, attnb, S);
    gemm_nn<64, 64, 2><<<dim3(D_MODEL / 64, S / 64), 256, 0, stream>>>(
        attnb, D_MODEL, D_MODEL, d_in[8], D_MODEL, 0, 0, d_in[9], 0,
        d_in[0], y, nullptr, D_MODEL, flags, 8, 9, 0, 1);
    ln2_kernel<<<S / 4, 256, 0, stream>>>(y, d_in[4], d_in[5], h2, flags);
    for (int p = 0; p < P; ++p) {
      if (Nc >= 1024) {
        gemm_nn<128, 128, 1><<<dim3(Nc / 128, S / 128), 256, 0, stream>>>(
            h2, D_MODEL, D_MODEL, d_in[10], D_FFN, 0, p * Nc, d_in[11], p * Nc,
            nullptr, nullptr, gbuf, Nc, flags, 10, 11, 0, 1);
      } else {
        gemm_nn<64, 64, 1><<<dim3(Nc / 64, S / 64), 256, 0, stream>>>(
            h2, D_MODEL, D_MODEL, d_in[10], D_FFN, 0, p * Nc, d_in[11], p * Nc,
            nullptr, nullptr, gbuf, Nc, flags, 10, 11, 0, 1);
      }
      gemm_nn<64, 64, 3><<<dim3(D_MODEL / 64, S / 64), 256, 0, stream>>>(
          gbuf, Nc, Nc, d_in[12], D_MODEL, p * Nc, 0, d_in[13], 0,
          nullptr, y, nullptr, D_MODEL, flags, 12, 13, 0, p == 0 ? 1 : 0);
    }
    convert_kernel<<<(int)((sD + 255) / 256), 256, 0, stream>>>(y, d_out, flags, (int)sD);
  }
}

// Round 4
// 182.953 us; speedup vs baseline: 1.1209x; 1.0250x over previous
//
#include <hip/hip_runtime.h>
#include <math.h>

typedef float f32x4 __attribute__((ext_vector_type(4)));
typedef short s16x8 __attribute__((ext_vector_type(8)));
typedef unsigned short u16x8 __attribute__((ext_vector_type(8)));
typedef unsigned short ushort_t;
typedef unsigned int uint_t;

#define D_MODEL 512
#define N_HEADS 8
#define HEAD_D  64
#define D_FFN   2048

__device__ __forceinline__ float bf2f(unsigned short u) {
  union { unsigned int i; float f; } c; c.i = ((unsigned int)u) << 16; return c.f;
}
__device__ __forceinline__ unsigned short f2bf(float f) {
  union { float f; unsigned int i; } c; c.f = f;
  unsigned int x = c.i;
  return (unsigned short)((x + 0x7FFFu + ((x >> 16) & 1u)) >> 16);
}
__device__ __forceinline__ float ldx(const void* p, size_t i, int f) {
  return f ? ((const float*)p)[i] : bf2f(((const ushort_t*)p)[i]);
}

// ------------------------------------------------- fused dtype detector
// One tiny upfront kernel; every consumer pays a single scalar flags[] load.
// (R1/R2 lesson: inlining this probe per-block into consumer kernels costs
// ~13 µs of un-hidable tail latency across the chain — keep it amortized.)
struct DetectArgs { const void* p[14]; int n[14]; };

__global__ __launch_bounds__(256)
void detect_all(DetectArgs a, int* __restrict__ flags) {
  __shared__ int cnt[2];
  const int b = blockIdx.x;
  const int t = threadIdx.x;
  if (b == 1) { if (t == 0) flags[1] = 0; return; }
  if (t == 0) { cnt[0] = 0; cnt[1] = 0; }
  __syncthreads();
  const int n_u32 = a.n[b] >> 1;
  const int sample = n_u32 < 256 ? n_u32 : 256;
  if (t < sample) {
    uint_t u = ((const uint_t*)a.p[b])[t];
    if (u != 0u) {
      atomicAdd(&cnt[0], 1);
      int e = (u >> 7) & 0xFF;
      if (e >= 0x70 && e <= 0x83) atomicAdd(&cnt[1], 1);
    }
  }
  __syncthreads();
  if (t == 0) flags[b] = (cnt[0] >= 32 && cnt[1] * 4 <= cnt[0]) ? 1 : 0;
}

// ------------------------------------------------- prep: weight convert+transpose AND ln1
// Independent work merged into one launch (flags-based: no per-block probes).
struct WDesc { const void* src; ushort_t* dst; int Kd, Nd, flag, tile0; };

__global__ __launch_bounds__(256)
void prep_kernel(WDesc w0, WDesc w1, WDesc w2, WDesc w3, int nconv,
                 const void* __restrict__ x, const void* __restrict__ g,
                 const void* __restrict__ b, ushort_t* __restrict__ h1,
                 const int* __restrict__ flags) {
  __shared__ ushort_t tile[32][33];
  const int blk = blockIdx.x;
  if (blk >= nconv) {
    // ----- ln1 path (4 rows per block)
    const int fx = flags[0], fg = flags[2], fb = flags[3];
    const int row = (blk - nconv) * 4 + (threadIdx.x >> 6);
    const int lane = threadIdx.x & 63;
    float v[8], sum = 0.f, sq = 0.f;
#pragma unroll
    for (int i = 0; i < 8; ++i) {
      v[i] = ldx(x, (size_t)row * D_MODEL + lane * 8 + i, fx);
      sum += v[i]; sq += v[i] * v[i];
    }
#pragma unroll
    for (int o = 32; o > 0; o >>= 1) { sum += __shfl_xor(sum, o); sq += __shfl_xor(sq, o); }
    const float mu = sum * (1.0f / D_MODEL);
    const float var = sq * (1.0f / D_MODEL) - mu * mu;
    const float rstd = rsqrtf(var + 1e-5f);
#pragma unroll
    for (int i = 0; i < 8; ++i) {
      int c = lane * 8 + i;
      h1[(size_t)row * D_MODEL + c] =
          f2bf((v[i] - mu) * rstd * ldx(g, c, fg) + ldx(b, c, fb));
    }
    return;
  }
  // ----- weight convert+transpose path
  WDesc d = (blk < w1.tile0) ? w0 : (blk < w2.tile0) ? w1 : (blk < w3.tile0) ? w2 : w3;
  const int lt = blk - d.tile0;
  const int tn = d.Nd / 32;
  const int bk = lt / tn, bn = lt % tn;
  const int f = flags[d.flag];
  const int tx = threadIdx.x & 31, ty = threadIdx.x >> 5;
#pragma unroll
  for (int r = 0; r < 4; ++r) {
    int k = bk * 32 + ty * 4 + r;
    tile[ty * 4 + r][tx] = f2bf(ldx(d.src, (size_t)k * d.Nd + bn * 32 + tx, f));
  }
  __syncthreads();
#pragma unroll
  for (int r = 0; r < 4; ++r) {
    int n = bn * 32 + ty * 4 + r;
    d.dst[(size_t)n * d.Kd + bk * 32 + tx] = tile[tx][ty * 4 + r];
  }
}

// ------------------------------------------------- LN kernels
__global__ __launch_bounds__(256)
void ln1_kernel(const void* __restrict__ x, const void* __restrict__ g,
                const void* __restrict__ b, ushort_t* __restrict__ out,
                const int* __restrict__ flags) {
  const int fx = flags[0], fg = flags[2], fb = flags[3];
  const int row = blockIdx.x * 4 + (threadIdx.x >> 6);
  const int lane = threadIdx.x & 63;
  float v[8], sum = 0.f, sq = 0.f;
#pragma unroll
  for (int i = 0; i < 8; ++i) {
    v[i] = ldx(x, (size_t)row * D_MODEL + lane * 8 + i, fx);
    sum += v[i]; sq += v[i] * v[i];
  }
#pragma unroll
  for (int o = 32; o > 0; o >>= 1) { sum += __shfl_xor(sum, o); sq += __shfl_xor(sq, o); }
  const float mu = sum * (1.0f / D_MODEL);
  const float var = sq * (1.0f / D_MODEL) - mu * mu;
  const float rstd = rsqrtf(var + 1e-5f);
#pragma unroll
  for (int i = 0; i < 8; ++i) {
    int c = lane * 8 + i;
    out[(size_t)row * D_MODEL + c] =
        f2bf((v[i] - mu) * rstd * ldx(g, c, fg) + ldx(b, c, fb));
  }
}

__global__ __launch_bounds__(256)
void ln2_kernel(const float* __restrict__ y, const void* __restrict__ g,
                const void* __restrict__ b, ushort_t* __restrict__ out,
                const int* __restrict__ flags) {
  const int fg = flags[4], fb = flags[5];
  const int row = blockIdx.x * 4 + (threadIdx.x >> 6);
  const int lane = threadIdx.x & 63;
  float v[8], sum = 0.f, sq = 0.f;
#pragma unroll
  for (int i = 0; i < 8; ++i) {
    v[i] = y[(size_t)row * D_MODEL + lane * 8 + i];
    sum += v[i]; sq += v[i] * v[i];
  }
#pragma unroll
  for (int o = 32; o > 0; o >>= 1) { sum += __shfl_xor(sum, o); sq += __shfl_xor(sq, o); }
  const float mu = sum * (1.0f / D_MODEL);
  const float var = sq * (1.0f / D_MODEL) - mu * mu;
  const float rstd = rsqrtf(var + 1e-5f);
#pragma unroll
  for (int i = 0; i < 8; ++i) {
    int c = lane * 8 + i;
    out[(size_t)row * D_MODEL + c] =
        f2bf((v[i] - mu) * rstd * ldx(g, c, fg) + ldx(b, c, fb));
  }
}

// ------------------------------------------------- pipelined MFMA GEMM, BK=64
// R4: double-buffered LDS with XOR-swizzled 16B granules instead of padding.
//  - granule swizzle: elem (row, k) lives at granule (k>>3)^(row&7) — rows
//    stay 128 B (16B-aligned, b128 ops intact), fragment reads hit 32 banks
//    2-way (free, m136), staging writes same pattern as the padded layout
//    (measured 0 conflicts).
//  - LDS 2x(BM+BN)x128B = 24 KB (32x64) -> still 6 blocks/CU. R1's dbuf
//    failed because it ALSO grew LDS via padding + swapped the staging path;
//    this keeps the R0 reg-staged gload/swrite pipeline intact.
//  - ONE barrier per K-step (was two): with two buffers, nobody overwrites
//    the tile others are still reading, so the read->write barrier is gone.
// EPI: 0 = +bias -> bf16            1 = gelu(+bias) -> bf16
//      2 = y[off] = v+bias+res      3 = y[off] += v (+bias if addb)
//      4 = out[off] = y[off] + v (+bias if addb; dtype per flags[ires])
template <int BM, int BN, int EPI>
__global__ __launch_bounds__(256)
void gemm_bt(const ushort_t* __restrict__ A, int lda,
             const ushort_t* __restrict__ BT, int ldb, int K,
             const void* __restrict__ bias, int bias_off,
             const void* __restrict__ res,
             float* __restrict__ yacc,
             ushort_t* __restrict__ out_bf, int ldo,
             const int* __restrict__ flags, int ibias, int ires, int addb) {
  constexpr int BK = 64;
  constexpr int FM = BM / 32, FN = BN / 32;
  constexpr int AG = BM / 32, BG = BN / 32;   // staging groups of 32 rows
  __shared__ __attribute__((aligned(16))) ushort_t As[2][BM][64];
  __shared__ __attribute__((aligned(16))) ushort_t Bs[2][BN][64];

  const int t = threadIdx.x;
  const int lane = t & 63, wave = t >> 6;
  const int wm = wave >> 1, wn = wave & 1;
  const int q = lane >> 4, lm = lane & 15;
  const int m0 = blockIdx.y * BM, n0 = blockIdx.x * BN;
  const int srow = t >> 3, sslot = t & 7;   // 32 rows x 8 granules per pass
  const int wslot = (sslot ^ (srow & 7)) * 8;  // swizzled write column
  const int xorg = lm & 7;                   // fragment-read swizzle (row&7==lm&7)

  f32x4 acc[FM][FN];
#pragma unroll
  for (int i = 0; i < FM; ++i)
#pragma unroll
    for (int j = 0; j < FN; ++j) acc[i][j] = (f32x4)(0.0f);

  u16x8 av[AG], bv[BG];

  auto gload = [&](int k0) {
#pragma unroll
    for (int r = 0; r < AG; ++r)
      av[r] = *(const u16x8*)(A + (size_t)(m0 + r * 32 + srow) * lda + k0 + sslot * 8);
#pragma unroll
    for (int r = 0; r < BG; ++r)
      bv[r] = *(const u16x8*)(BT + (size_t)(n0 + r * 32 + srow) * ldb + k0 + sslot * 8);
  };
  auto swrite = [&](int buf) {
#pragma unroll
    for (int r = 0; r < AG; ++r) *(u16x8*)&As[buf][r * 32 + srow][wslot] = av[r];
#pragma unroll
    for (int r = 0; r < BG; ++r) *(u16x8*)&Bs[buf][r * 32 + srow][wslot] = bv[r];
  };
  auto frag_mfma = [&](int buf, int kh) {
    s16x8 af[FM], bf[FN];
    const int rcol = ((kh * 4 + q) ^ xorg) * 8;   // swizzled read column
#pragma unroll
    for (int i = 0; i < FM; ++i)
      af[i] = *(const s16x8*)&As[buf][wm * (BM / 2) + i * 16 + lm][rcol];
#pragma unroll
    for (int j = 0; j < FN; ++j)
      bf[j] = *(const s16x8*)&Bs[buf][wn * (BN / 2) + j * 16 + lm][rcol];
#pragma unroll
    for (int i = 0; i < FM; ++i)
#pragma unroll
      for (int j = 0; j < FN; ++j)
        acc[i][j] = __builtin_amdgcn_mfma_f32_16x16x32_bf16(af[i], bf[j], acc[i][j], 0, 0, 0);
  };

  gload(0);
  swrite(0);
  __syncthreads();
  int buf = 0;
  for (int k0 = BK; k0 < K; k0 += BK) {
    gload(k0);            // next tile in flight over current tile's MFMA
    frag_mfma(buf, 0);
    frag_mfma(buf, 1);
    swrite(buf ^ 1);      // other buffer: nobody reads it this iteration
    __syncthreads();      // ONE barrier per K-step
    buf ^= 1;
  }
  frag_mfma(buf, 0);
  frag_mfma(buf, 1);

  const int fbias = flags[ibias];
#pragma unroll
  for (int i = 0; i < FM; ++i) {
#pragma unroll
    for (int j = 0; j < FN; ++j) {
      const int colg = n0 + wn * (BN / 2) + j * 16 + lm;
      float bb = 0.0f;
      if (EPI <= 2 || addb) bb = ldx(bias, bias_off + colg, fbias);
#pragma unroll
      for (int r = 0; r < 4; ++r) {
        const int rowg = m0 + wm * (BM / 2) + i * 16 + q * 4 + r;
        float v = acc[i][j][r] + bb;
        const size_t off = (size_t)rowg * ldo + colg;
        if constexpr (EPI == 0) {
          out_bf[off] = f2bf(v);
        } else if constexpr (EPI == 1) {
          out_bf[off] = f2bf(0.5f * v * (1.0f + erff(v * 0.70710678f)));
        } else if constexpr (EPI == 2) {
          yacc[off] = v + ldx(res, off, flags[ires]);
        } else if constexpr (EPI == 3) {
          yacc[off] += v;
        } else {
          float fin = yacc[off] + v;
          if (flags[ires]) ((float*)(void*)out_bf)[off] = fin;
          else             out_bf[off] = f2bf(fin);
        }
      }
    }
  }
}

// ------------------------------------------------- legacy GEMM (fallback path, r6-proven)
template <int BM, int BN, int EPI>
__global__ __launch_bounds__(256)
void gemm_nn(const ushort_t* __restrict__ A, int lda, int K,
             const void* __restrict__ B, int ldb, int brow0, int bcol0,
             const void* __restrict__ bias, int bias_off,
             const void* __restrict__ res,
             float* __restrict__ yacc,
             ushort_t* __restrict__ out_bf, int ldo,
             const int* __restrict__ flags, int iB, int ibias, int ires, int addb) {
  constexpr int BK = 32;
  constexpr int FM = BM / 32, FN = BN / 32;
  __shared__ __attribute__((aligned(16))) ushort_t As[BM][40];
  __shared__ ushort_t Bs[BK][BN + 2];
  const int t = threadIdx.x;
  const int lane = t & 63, wave = t >> 6;
  const int wm = wave >> 1, wn = wave & 1;
  const int m0 = blockIdx.y * BM, n0 = blockIdx.x * BN;
  const int fB = flags[iB], fbias = flags[ibias];
  f32x4 acc[FM][FN];
#pragma unroll
  for (int i = 0; i < FM; ++i)
#pragma unroll
    for (int j = 0; j < FN; ++j) acc[i][j] = (f32x4)(0.0f);
  const int q = lane >> 4, lm = lane & 15;
  const int arow_s = t >> 2, aslot = t & 3;
  for (int k0 = 0; k0 < K; k0 += BK) {
    __syncthreads();
#pragma unroll
    for (int r = 0; r < BM / 64; ++r) {
      int row = r * 64 + arow_s;
      *(u16x8*)&As[row][aslot * 8] =
          *(const u16x8*)(A + (size_t)(m0 + row) * lda + k0 + aslot * 8);
    }
#pragma unroll
    for (int e = 0; e < (BK * BN) / 256; ++e) {
      int id = e * 256 + t;
      int k = id / BN, n = id % BN;
      Bs[k][n] = f2bf(ldx(B, (size_t)(brow0 + k0 + k) * ldb + bcol0 + n0 + n, fB));
    }
    __syncthreads();
    s16x8 af[FM], bf[FN];
#pragma unroll
    for (int i = 0; i < FM; ++i)
      af[i] = *(const s16x8*)&As[wm * (BM / 2) + i * 16 + lm][q * 8];
#pragma unroll
    for (int j = 0; j < FN; ++j) {
      int nl = wn * (BN / 2) + j * 16 + lm;
      u16x8 tmp;
#pragma unroll
      for (int f = 0; f < 8; ++f) tmp[f] = Bs[q * 8 + f][nl];
      bf[j] = __builtin_bit_cast(s16x8, tmp);
    }
#pragma unroll
    for (int i = 0; i < FM; ++i)
#pragma unroll
      for (int j = 0; j < FN; ++j)
        acc[i][j] = __builtin_amdgcn_mfma_f32_16x16x32_bf16(af[i], bf[j], acc[i][j], 0, 0, 0);
  }
#pragma unroll
  for (int i = 0; i < FM; ++i) {
#pragma unroll
    for (int j = 0; j < FN; ++j) {
      const int col = wn * (BN / 2) + j * 16 + lm;
      float bb = 0.0f;
      if (EPI != 3 || addb) bb = ldx(bias, bias_off + n0 + col, fbias);
#pragma unroll
      for (int r = 0; r < 4; ++r) {
        const int rowg = m0 + wm * (BM / 2) + i * 16 + q * 4 + r;
        float v = acc[i][j][r] + bb;
        if constexpr (EPI == 0) {
          out_bf[(size_t)rowg * ldo + n0 + col] = f2bf(v);
        } else if constexpr (EPI == 1) {
          out_bf[(size_t)rowg * ldo + n0 + col] =
              f2bf(0.5f * v * (1.0f + erff(v * 0.70710678f)));
        } else if constexpr (EPI == 2) {
          const size_t off = (size_t)rowg * D_MODEL + n0 + col;
          yacc[off] = v + ldx(res, off, flags[ires]);
        } else {
          const size_t off = (size_t)rowg * D_MODEL + n0 + col;
          yacc[off] += v;
        }
      }
    }
  }
}

// ------------------------------------------------- attention (r14 coalesced-K)
// XCD-aware block swizzle (T1): neutral-vs-R0 at S=2048 but mechanistically
// sound (one head's 512 KB K/V slice per XCD L2) and harmless — kept.
__device__ __forceinline__ int key_index(int s, int j, int S) {
  int p;
  if (j < 64)       p = s + j - 32;
  else if (j < 102) p = s + (j - 83) * 64;
  else              p = ((j - 102) * (S - 1)) / 25;
  return min(max(p, 0), S - 1);
}

__global__ __launch_bounds__(256, 4)
void attn_kernel(const ushort_t* __restrict__ qkv, ushort_t* __restrict__ out, int S) {
  const int wave = threadIdx.x >> 6, lane = threadIdx.x & 63;
  const int nb = gridDim.x;
  int bid = blockIdx.x;
  if ((nb & 7) == 0) bid = (bid & 7) * (nb >> 3) + (bid >> 3);  // XCD swizzle (bijective)
  const int pair = bid * 4 + wave;          // pair = h*S + s
  const int h = pair / S;
  const int s = pair - h * S;
  const int g = lane >> 3, d8 = (lane & 7) * 8;

  int koff[16];
#pragma unroll
  for (int r = 0; r < 16; ++r)
    koff[r] = key_index(s, r * 8 + g, S) * (3 * D_MODEL);

  u16x8 qv8 = *(const u16x8*)(qkv + (size_t)s * (3 * D_MODEL) + h * HEAD_D + d8);
  float qf[8];
#pragma unroll
  for (int e = 0; e < 8; ++e) qf[e] = bf2f(qv8[e]);

  const ushort_t* kbase = qkv + D_MODEL + h * HEAD_D + d8;
  float pr[16];
  {
    u16x8 kv[8];
#pragma unroll
    for (int r = 0; r < 8; ++r) kv[r] = *(const u16x8*)(kbase + koff[r]);
#pragma unroll
    for (int r = 0; r < 16; ++r) {
      u16x8 cur = kv[r & 7];
      if (r < 8) kv[r & 7] = *(const u16x8*)(kbase + koff[r + 8]);
      float d = 0.f;
#pragma unroll
      for (int e = 0; e < 8; ++e) d += qf[e] * bf2f(cur[e]);
      d += __shfl_xor(d, 1);
      d += __shfl_xor(d, 2);
      d += __shfl_xor(d, 4);
      pr[r] = d * 0.125f;
    }
  }

  float mx = pr[0];
#pragma unroll
  for (int r = 1; r < 16; ++r) mx = fmaxf(mx, pr[r]);
#pragma unroll
  for (int m = 8; m <= 32; m <<= 1) mx = fmaxf(mx, __shfl_xor(mx, m));
  float sm = 0.f;
#pragma unroll
  for (int r = 0; r < 16; ++r) { pr[r] = __expf(pr[r] - mx); sm += pr[r]; }
#pragma unroll
  for (int m = 8; m <= 32; m <<= 1) sm += __shfl_xor(sm, m);
  const float inv = 1.0f / sm;

  const ushort_t* vbase = qkv + 2 * D_MODEL + h * HEAD_D + d8;
  float oacc[8];
#pragma unroll
  for (int e = 0; e < 8; ++e) oacc[e] = 0.f;
  {
    u16x8 vv[8];
#pragma unroll
    for (int r = 0; r < 8; ++r) vv[r] = *(const u16x8*)(vbase + koff[r]);
#pragma unroll
    for (int r = 0; r < 16; ++r) {
      u16x8 cv = vv[r & 7];
      float cp = pr[r] * inv;
      if (r < 8) vv[r & 7] = *(const u16x8*)(vbase + koff[r + 8]);
#pragma unroll
      for (int e = 0; e < 8; ++e) oacc[e] += cp * bf2f(cv[e]);
    }
  }
#pragma unroll
  for (int m = 8; m <= 32; m <<= 1)
#pragma unroll
    for (int e = 0; e < 8; ++e) oacc[e] += __shfl_xor(oacc[e], m);

  if (lane < 8) {
    u16x8 ov;
#pragma unroll
    for (int e = 0; e < 8; ++e) ov[e] = f2bf(oacc[e]);
    *(u16x8*)(out + (size_t)s * D_MODEL + h * HEAD_D + d8) = ov;
  }
}

// ------------------------------------------------- final convert (fallback only)
__global__ __launch_bounds__(256)
void convert_kernel(const float* __restrict__ y, void* __restrict__ out,
                    const int* __restrict__ flags, int n) {
  const int fout = flags[0];
  int i = blockIdx.x * 256 + threadIdx.x;
  if (i < n) {
    float v = y[i];
    if (fout) ((float*)out)[i] = v;
    else      ((ushort_t*)out)[i] = f2bf(v);
  }
}

// ------------------------------------------------- launch
extern "C" void kernel_launch(void* const* d_in, const int* in_sizes, int n_in,
                              void* d_out, int out_size, void* d_ws, size_t ws_size,
                              hipStream_t stream) {
  const int S = in_sizes[0] / D_MODEL;    // 2048
  const size_t sD = (size_t)S * D_MODEL;
  char* ws = (char*)d_ws;

  DetectArgs da;
  for (int i = 0; i < 14; ++i) { da.p[i] = d_in[i]; da.n[i] = in_sizes[i]; }

  ushort_t* h1    = (ushort_t*)d_out;
  ushort_t* attnb = (ushort_t*)d_out;
  ushort_t* h2    = (ushort_t*)d_out;

  const size_t MB = 1024 * 1024;
  if (ws_size >= 12 * MB + 64) {
    const int P  = (ws_size >= 20 * MB) ? 1 : 2;
    const int Nc = D_FFN / P;
    char* wbase = ws + (P == 1 ? 12 : 6) * MB;

    ushort_t* qkv   = (ushort_t*)ws;                       // [0,6M)
    float*    y     = (float*)ws;                          // [0,4M) after qkv dies
    ushort_t* gbuf  = (ushort_t*)(ws + 4 * MB);            // S*Nc bf16 (4 or 8 MB)
    ushort_t* wqkvT = (ushort_t*)wbase;                    // 1.5 MB
    ushort_t* woT   = (ushort_t*)(wbase + 1 * MB + 512 * 1024);  // 0.5 MB
    ushort_t* w1T   = (ushort_t*)(wbase + 2 * MB);         // 2 MB
    ushort_t* w2T   = (ushort_t*)(wbase + 4 * MB);         // 2 MB
    int*      flags = (int*)(wbase + 6 * MB);

    detect_all<<<14, 256, 0, stream>>>(da, flags);

    WDesc dq  = { d_in[6],  wqkvT, D_MODEL, 3 * D_MODEL, 6,  0 };
    WDesc dwo = { d_in[8],  woT,   D_MODEL, D_MODEL,     8,  768 };
    WDesc dw1 = { d_in[10], w1T,   D_MODEL, D_FFN,       10, 1024 };
    WDesc dw2 = { d_in[12], w2T,   D_FFN,   D_MODEL,     12, 2048 };

    // K2: weight convert (3072 blocks) + ln1 (S/4 blocks), flags-based
    prep_kernel<<<3072 + S / 4, 256, 0, stream>>>(
        dq, dwo, dw1, dw2, 3072, d_in[0], d_in[2], d_in[3], h1, flags);

    // GEMM1: h1 @ wqkv + bqkv -> qkv  (32x64, 1536 blocks, 6/CU)
    gemm_bt<32, 64, 0><<<dim3(24, S / 32), 256, 0, stream>>>(
        h1, D_MODEL, wqkvT, D_MODEL, D_MODEL, d_in[7], 0,
        nullptr, nullptr, qkv, 3 * D_MODEL, flags, 7, 0, 1);

    attn_kernel<<<(S * N_HEADS) / 4, 256, 0, stream>>>(qkv, attnb, S);

    // GEMM2: attnb @ wo + bo + x -> y (32x32, 1024 blocks, 4/CU)
    gemm_bt<32, 32, 2><<<dim3(16, S / 32), 256, 0, stream>>>(
        attnb, D_MODEL, woT, D_MODEL, D_MODEL, d_in[9], 0,
        d_in[0], y, nullptr, D_MODEL, flags, 9, 0, 1);

    ln2_kernel<<<S / 4, 256, 0, stream>>>(y, d_in[4], d_in[5], h2, flags);

    if (P == 1) {
      // GEMM3: h2 @ w1 + b1 -> gelu -> gbuf  (32x64, 2048 blocks, 8/CU)
      gemm_bt<32, 64, 1><<<dim3(D_FFN / 64, S / 32), 256, 0, stream>>>(
          h2, D_MODEL, w1T, D_MODEL, D_MODEL,
          d_in[11], 0, nullptr, nullptr, gbuf, D_FFN, flags, 11, 0, 1);
      // GEMM4: out = y + gbuf @ w2 + b2  (K=2048; 32x32, 1024 blocks, 4/CU)
      gemm_bt<32, 32, 4><<<dim3(16, S / 32), 256, 0, stream>>>(
          gbuf, D_FFN, w2T, D_FFN, D_FFN, d_in[13], 0,
          nullptr, y, (ushort_t*)d_out, D_MODEL, flags, 13, 0, 1);
    } else {
      gemm_bt<32, 64, 1><<<dim3(Nc / 64, S / 32), 256, 0, stream>>>(
          h2, D_MODEL, w1T, D_MODEL, D_MODEL,
          d_in[11], 0, nullptr, nullptr, gbuf, Nc, flags, 11, 0, 1);
      gemm_bt<32, 32, 3><<<dim3(16, S / 32), 256, 0, stream>>>(
          gbuf, Nc, w2T, D_FFN, Nc, d_in[13], 0,
          nullptr, y, nullptr, D_MODEL, flags, 13, 0, 1);
      gemm_bt<32, 64, 1><<<dim3(Nc / 64, S / 32), 256, 0, stream>>>(
          h2, D_MODEL, w1T + (size_t)Nc * D_MODEL, D_MODEL, D_MODEL,
          d_in[11], Nc, nullptr, nullptr, gbuf, Nc, flags, 11, 0, 1);
      gemm_bt<32, 32, 4><<<dim3(16, S / 32), 256, 0, stream>>>(
          gbuf, Nc, w2T + (size_t)Nc, D_FFN, Nc, d_in[13], 0,
          nullptr, y, (ushort_t*)d_out, D_MODEL, flags, 13, 0, 0);
    }
  } else {
    // fallback: round-6 proven path
    int P;
    if      (ws_size >= 12ull * MB + 4096) P = 1;
    else if (ws_size >=  8ull * MB + 4096) P = 2;
    else                                   P = 4;
    const int Nc = D_FFN / P;
    const size_t gbuf_bytes = (size_t)S * Nc * 2;
    const size_t qkv_bytes  = 3 * sD * 2;
    const size_t fo = 4ull * sD + gbuf_bytes;
    const size_t flags_pos = (qkv_bytes > fo ? qkv_bytes : fo);

    ushort_t* qkv  = (ushort_t*)ws;
    float*    y    = (float*)ws;
    ushort_t* gbuf = (ushort_t*)(ws + 4 * sD);
    int*      flags = (int*)(ws + flags_pos);

    detect_all<<<14, 256, 0, stream>>>(da, flags);
    ln1_kernel<<<S / 4, 256, 0, stream>>>(d_in[0], d_in[2], d_in[3], h1, flags);
    gemm_nn<128, 128, 0><<<dim3((3 * D_MODEL) / 128, S / 128), 256, 0, stream>>>(
        h1, D_MODEL, D_MODEL, d_in[6], 3 * D_MODEL, 0, 0, d_in[7], 0,
        nullptr, nullptr, qkv, 3 * D_MODEL, flags, 6, 7, 0, 1);
    attn_kernel<<<(S * N_HEADS) / 4, 256, 0, stream>>>(qkv, attnb, S);
    gemm_nn<64, 64, 2><<<dim3(D_MODEL / 64, S / 64), 256, 0, stream>>>(
        attnb, D_MODEL, D_MODEL, d_in[8], D_MODEL, 0, 0, d_in[9], 0,
        d_in[0], y, nullptr, D_MODEL, flags, 8, 9, 0, 1);
    ln2_kernel<<<S / 4, 256, 0, stream>>>(y, d_in[4], d_in[5], h2, flags);
    for (int p = 0; p < P; ++p) {
      if (Nc >= 1024) {
        gemm_nn<128, 128, 1><<<dim3(Nc / 128, S / 128), 256, 0, stream>>>(
            h2, D_MODEL, D_MODEL, d_in[10], D_FFN, 0, p * Nc, d_in[11], p * Nc,
            nullptr, nullptr, gbuf, Nc, flags, 10, 11, 0, 1);
      } else {
        gemm_nn<64, 64, 1><<<dim3(Nc / 64, S / 64), 256, 0, stream>>>(
            h2, D_MODEL, D_MODEL, d_in[10], D_FFN, 0, p * Nc, d_in[11], p * Nc,
            nullptr, nullptr, gbuf, Nc, flags, 10, 11, 0, 1);
      }
      gemm_nn<64, 64, 3><<<dim3(D_MODEL / 64, S / 64), 256, 0, stream>>>(
          gbuf, Nc, Nc, d_in[12], D_MODEL, p * Nc, 0, d_in[13], 0,
          nullptr, y, nullptr, D_MODEL, flags, 12, 13, 0, p == 0 ? 1 : 0);
    }
    convert_kernel<<<(int)((sD + 255) / 256), 256, 0, stream>>>(y, d_out, flags, (int)sD);
  }
}

// Round 5
// 180.771 us; speedup vs baseline: 1.1345x; 1.0121x over previous
//
#include <hip/hip_runtime.h>
#include <math.h>

typedef float f32x4 __attribute__((ext_vector_type(4)));
typedef short s16x8 __attribute__((ext_vector_type(8)));
typedef unsigned short u16x8 __attribute__((ext_vector_type(8)));
typedef unsigned short ushort_t;
typedef unsigned int uint_t;

#define D_MODEL 512
#define N_HEADS 8
#define HEAD_D  64
#define D_FFN   2048

__device__ __forceinline__ float bf2f(unsigned short u) {
  union { unsigned int i; float f; } c; c.i = ((unsigned int)u) << 16; return c.f;
}
__device__ __forceinline__ unsigned short f2bf(float f) {
  union { float f; unsigned int i; } c; c.f = f;
  unsigned int x = c.i;
  return (unsigned short)((x + 0x7FFFu + ((x >> 16) & 1u)) >> 16);
}
__device__ __forceinline__ float ldx(const void* p, size_t i, int f) {
  return f ? ((const float*)p)[i] : bf2f(((const ushort_t*)p)[i]);
}

// ------------------------------------------------- fused dtype detector
// One tiny upfront kernel; every consumer pays a single scalar flags[] load.
// (R1/R2 lesson: inlining this probe per-block into consumer kernels costs
// ~13 µs of un-hidable tail latency across the chain — keep it amortized.)
struct DetectArgs { const void* p[14]; int n[14]; };

__global__ __launch_bounds__(256)
void detect_all(DetectArgs a, int* __restrict__ flags) {
  __shared__ int cnt[2];
  const int b = blockIdx.x;
  const int t = threadIdx.x;
  if (b == 1) { if (t == 0) flags[1] = 0; return; }
  if (t == 0) { cnt[0] = 0; cnt[1] = 0; }
  __syncthreads();
  const int n_u32 = a.n[b] >> 1;
  const int sample = n_u32 < 256 ? n_u32 : 256;
  if (t < sample) {
    uint_t u = ((const uint_t*)a.p[b])[t];
    if (u != 0u) {
      atomicAdd(&cnt[0], 1);
      int e = (u >> 7) & 0xFF;
      if (e >= 0x70 && e <= 0x83) atomicAdd(&cnt[1], 1);
    }
  }
  __syncthreads();
  if (t == 0) flags[b] = (cnt[0] >= 32 && cnt[1] * 4 <= cnt[0]) ? 1 : 0;
}

// ------------------------------------------------- prep: weight convert+transpose AND ln1
// Independent work merged into one launch (flags-based: no per-block probes).
struct WDesc { const void* src; ushort_t* dst; int Kd, Nd, flag, tile0; };

__global__ __launch_bounds__(256)
void prep_kernel(WDesc w0, WDesc w1, WDesc w2, WDesc w3, int nconv,
                 const void* __restrict__ x, const void* __restrict__ g,
                 const void* __restrict__ b, ushort_t* __restrict__ h1,
                 const int* __restrict__ flags) {
  __shared__ ushort_t tile[32][33];
  const int blk = blockIdx.x;
  if (blk >= nconv) {
    // ----- ln1 path (4 rows per block)
    const int fx = flags[0], fg = flags[2], fb = flags[3];
    const int row = (blk - nconv) * 4 + (threadIdx.x >> 6);
    const int lane = threadIdx.x & 63;
    float v[8], sum = 0.f, sq = 0.f;
#pragma unroll
    for (int i = 0; i < 8; ++i) {
      v[i] = ldx(x, (size_t)row * D_MODEL + lane * 8 + i, fx);
      sum += v[i]; sq += v[i] * v[i];
    }
#pragma unroll
    for (int o = 32; o > 0; o >>= 1) { sum += __shfl_xor(sum, o); sq += __shfl_xor(sq, o); }
    const float mu = sum * (1.0f / D_MODEL);
    const float var = sq * (1.0f / D_MODEL) - mu * mu;
    const float rstd = rsqrtf(var + 1e-5f);
#pragma unroll
    for (int i = 0; i < 8; ++i) {
      int c = lane * 8 + i;
      h1[(size_t)row * D_MODEL + c] =
          f2bf((v[i] - mu) * rstd * ldx(g, c, fg) + ldx(b, c, fb));
    }
    return;
  }
  // ----- weight convert+transpose path
  WDesc d = (blk < w1.tile0) ? w0 : (blk < w2.tile0) ? w1 : (blk < w3.tile0) ? w2 : w3;
  const int lt = blk - d.tile0;
  const int tn = d.Nd / 32;
  const int bk = lt / tn, bn = lt % tn;
  const int f = flags[d.flag];
  const int tx = threadIdx.x & 31, ty = threadIdx.x >> 5;
#pragma unroll
  for (int r = 0; r < 4; ++r) {
    int k = bk * 32 + ty * 4 + r;
    tile[ty * 4 + r][tx] = f2bf(ldx(d.src, (size_t)k * d.Nd + bn * 32 + tx, f));
  }
  __syncthreads();
#pragma unroll
  for (int r = 0; r < 4; ++r) {
    int n = bn * 32 + ty * 4 + r;
    d.dst[(size_t)n * d.Kd + bk * 32 + tx] = tile[tx][ty * 4 + r];
  }
}

// ------------------------------------------------- LN kernels
__global__ __launch_bounds__(256)
void ln1_kernel(const void* __restrict__ x, const void* __restrict__ g,
                const void* __restrict__ b, ushort_t* __restrict__ out,
                const int* __restrict__ flags) {
  const int fx = flags[0], fg = flags[2], fb = flags[3];
  const int row = blockIdx.x * 4 + (threadIdx.x >> 6);
  const int lane = threadIdx.x & 63;
  float v[8], sum = 0.f, sq = 0.f;
#pragma unroll
  for (int i = 0; i < 8; ++i) {
    v[i] = ldx(x, (size_t)row * D_MODEL + lane * 8 + i, fx);
    sum += v[i]; sq += v[i] * v[i];
  }
#pragma unroll
  for (int o = 32; o > 0; o >>= 1) { sum += __shfl_xor(sum, o); sq += __shfl_xor(sq, o); }
  const float mu = sum * (1.0f / D_MODEL);
  const float var = sq * (1.0f / D_MODEL) - mu * mu;
  const float rstd = rsqrtf(var + 1e-5f);
#pragma unroll
  for (int i = 0; i < 8; ++i) {
    int c = lane * 8 + i;
    out[(size_t)row * D_MODEL + c] =
        f2bf((v[i] - mu) * rstd * ldx(g, c, fg) + ldx(b, c, fb));
  }
}

__global__ __launch_bounds__(256)
void ln2_kernel(const float* __restrict__ y, const void* __restrict__ g,
                const void* __restrict__ b, ushort_t* __restrict__ out,
                const int* __restrict__ flags) {
  const int fg = flags[4], fb = flags[5];
  const int row = blockIdx.x * 4 + (threadIdx.x >> 6);
  const int lane = threadIdx.x & 63;
  float v[8], sum = 0.f, sq = 0.f;
#pragma unroll
  for (int i = 0; i < 8; ++i) {
    v[i] = y[(size_t)row * D_MODEL + lane * 8 + i];
    sum += v[i]; sq += v[i] * v[i];
  }
#pragma unroll
  for (int o = 32; o > 0; o >>= 1) { sum += __shfl_xor(sum, o); sq += __shfl_xor(sq, o); }
  const float mu = sum * (1.0f / D_MODEL);
  const float var = sq * (1.0f / D_MODEL) - mu * mu;
  const float rstd = rsqrtf(var + 1e-5f);
#pragma unroll
  for (int i = 0; i < 8; ++i) {
    int c = lane * 8 + i;
    out[(size_t)row * D_MODEL + c] =
        f2bf((v[i] - mu) * rstd * ldx(g, c, fg) + ldx(b, c, fb));
  }
}

// ------------------------------------------------- pipelined MFMA GEMM, BK=64
// R5: write-early double buffer. R4 staged next-tile at iteration END, so the
// gload->swrite vmcnt wait was covered only by ~4 MFMA (<< L2 ~200cy). Now the
// swrite of tile t happens at the START of iteration t — the loads issued in
// iteration t-1 get a full K-step (MFMA + barrier + other waves) of cover.
// Safe with a SINGLE register set and single barrier/K-step: the sync at the
// end of iter t-1 guarantees all reads of the target buffer completed.
//  - granule swizzle unchanged (elem (row,k) at granule (k>>3)^(row&7)):
//    b128 ops intact, fragment reads 2-way bank max (free, m136).
//  - LDS 2x(BM+BN)x128B = 24 KB (32x64) -> still 6 blocks/CU; zero extra VGPR
//    (a 2-deep second register set would cross the ~85-VGPR occupancy cliff).
// EPI: 0 = +bias -> bf16            1 = gelu(+bias) -> bf16
//      2 = y[off] = v+bias+res      3 = y[off] += v (+bias if addb)
//      4 = out[off] = y[off] + v (+bias if addb; dtype per flags[ires])
template <int BM, int BN, int EPI>
__global__ __launch_bounds__(256)
void gemm_bt(const ushort_t* __restrict__ A, int lda,
             const ushort_t* __restrict__ BT, int ldb, int K,
             const void* __restrict__ bias, int bias_off,
             const void* __restrict__ res,
             float* __restrict__ yacc,
             ushort_t* __restrict__ out_bf, int ldo,
             const int* __restrict__ flags, int ibias, int ires, int addb) {
  constexpr int BK = 64;
  constexpr int FM = BM / 32, FN = BN / 32;
  constexpr int AG = BM / 32, BG = BN / 32;   // staging groups of 32 rows
  __shared__ __attribute__((aligned(16))) ushort_t As[2][BM][64];
  __shared__ __attribute__((aligned(16))) ushort_t Bs[2][BN][64];

  const int t = threadIdx.x;
  const int lane = t & 63, wave = t >> 6;
  const int wm = wave >> 1, wn = wave & 1;
  const int q = lane >> 4, lm = lane & 15;
  const int m0 = blockIdx.y * BM, n0 = blockIdx.x * BN;
  const int srow = t >> 3, sslot = t & 7;   // 32 rows x 8 granules per pass
  const int wslot = (sslot ^ (srow & 7)) * 8;  // swizzled write column
  const int xorg = lm & 7;                   // fragment-read swizzle (row&7==lm&7)

  f32x4 acc[FM][FN];
#pragma unroll
  for (int i = 0; i < FM; ++i)
#pragma unroll
    for (int j = 0; j < FN; ++j) acc[i][j] = (f32x4)(0.0f);

  u16x8 av[AG], bv[BG];

  auto gload = [&](int k0) {
#pragma unroll
    for (int r = 0; r < AG; ++r)
      av[r] = *(const u16x8*)(A + (size_t)(m0 + r * 32 + srow) * lda + k0 + sslot * 8);
#pragma unroll
    for (int r = 0; r < BG; ++r)
      bv[r] = *(const u16x8*)(BT + (size_t)(n0 + r * 32 + srow) * ldb + k0 + sslot * 8);
  };
  auto swrite = [&](int buf) {
#pragma unroll
    for (int r = 0; r < AG; ++r) *(u16x8*)&As[buf][r * 32 + srow][wslot] = av[r];
#pragma unroll
    for (int r = 0; r < BG; ++r) *(u16x8*)&Bs[buf][r * 32 + srow][wslot] = bv[r];
  };
  auto frag_mfma = [&](int buf, int kh) {
    s16x8 af[FM], bf[FN];
    const int rcol = ((kh * 4 + q) ^ xorg) * 8;   // swizzled read column
#pragma unroll
    for (int i = 0; i < FM; ++i)
      af[i] = *(const s16x8*)&As[buf][wm * (BM / 2) + i * 16 + lm][rcol];
#pragma unroll
    for (int j = 0; j < FN; ++j)
      bf[j] = *(const s16x8*)&Bs[buf][wn * (BN / 2) + j * 16 + lm][rcol];
#pragma unroll
    for (int i = 0; i < FM; ++i)
#pragma unroll
      for (int j = 0; j < FN; ++j)
        acc[i][j] = __builtin_amdgcn_mfma_f32_16x16x32_bf16(af[i], bf[j], acc[i][j], 0, 0, 0);
  };

  const int NT = K / BK;
  gload(0);
  swrite(0);            // exposed vmcnt once (prologue only)
  __syncthreads();
  gload(BK);            // tile 1 in flight across the whole first K-step
  int buf = 0;
  for (int kt = 1; kt < NT; ++kt) {
    swrite(buf ^ 1);    // stage tile kt (issued last iteration: latency covered)
    if (kt + 1 < NT) gload((kt + 1) * BK);   // issue tile kt+1
    frag_mfma(buf, 0);  // compute tile kt-1
    frag_mfma(buf, 1);
    __syncthreads();    // ONE barrier per K-step
    buf ^= 1;
  }
  frag_mfma(buf, 0);    // compute tile NT-1
  frag_mfma(buf, 1);

  const int fbias = flags[ibias];
#pragma unroll
  for (int i = 0; i < FM; ++i) {
#pragma unroll
    for (int j = 0; j < FN; ++j) {
      const int colg = n0 + wn * (BN / 2) + j * 16 + lm;
      float bb = 0.0f;
      if (EPI <= 2 || addb) bb = ldx(bias, bias_off + colg, fbias);
#pragma unroll
      for (int r = 0; r < 4; ++r) {
        const int rowg = m0 + wm * (BM / 2) + i * 16 + q * 4 + r;
        float v = acc[i][j][r] + bb;
        const size_t off = (size_t)rowg * ldo + colg;
        if constexpr (EPI == 0) {
          out_bf[off] = f2bf(v);
        } else if constexpr (EPI == 1) {
          out_bf[off] = f2bf(0.5f * v * (1.0f + erff(v * 0.70710678f)));
        } else if constexpr (EPI == 2) {
          yacc[off] = v + ldx(res, off, flags[ires]);
        } else if constexpr (EPI == 3) {
          yacc[off] += v;
        } else {
          float fin = yacc[off] + v;
          if (flags[ires]) ((float*)(void*)out_bf)[off] = fin;
          else             out_bf[off] = f2bf(fin);
        }
      }
    }
  }
}

// ------------------------------------------------- legacy GEMM (fallback path, r6-proven)
template <int BM, int BN, int EPI>
__global__ __launch_bounds__(256)
void gemm_nn(const ushort_t* __restrict__ A, int lda, int K,
             const void* __restrict__ B, int ldb, int brow0, int bcol0,
             const void* __restrict__ bias, int bias_off,
             const void* __restrict__ res,
             float* __restrict__ yacc,
             ushort_t* __restrict__ out_bf, int ldo,
             const int* __restrict__ flags, int iB, int ibias, int ires, int addb) {
  constexpr int BK = 32;
  constexpr int FM = BM / 32, FN = BN / 32;
  __shared__ __attribute__((aligned(16))) ushort_t As[BM][40];
  __shared__ ushort_t Bs[BK][BN + 2];
  const int t = threadIdx.x;
  const int lane = t & 63, wave = t >> 6;
  const int wm = wave >> 1, wn = wave & 1;
  const int m0 = blockIdx.y * BM, n0 = blockIdx.x * BN;
  const int fB = flags[iB], fbias = flags[ibias];
  f32x4 acc[FM][FN];
#pragma unroll
  for (int i = 0; i < FM; ++i)
#pragma unroll
    for (int j = 0; j < FN; ++j) acc[i][j] = (f32x4)(0.0f);
  const int q = lane >> 4, lm = lane & 15;
  const int arow_s = t >> 2, aslot = t & 3;
  for (int k0 = 0; k0 < K; k0 += BK) {
    __syncthreads();
#pragma unroll
    for (int r = 0; r < BM / 64; ++r) {
      int row = r * 64 + arow_s;
      *(u16x8*)&As[row][aslot * 8] =
          *(const u16x8*)(A + (size_t)(m0 + row) * lda + k0 + aslot * 8);
    }
#pragma unroll
    for (int e = 0; e < (BK * BN) / 256; ++e) {
      int id = e * 256 + t;
      int k = id / BN, n = id % BN;
      Bs[k][n] = f2bf(ldx(B, (size_t)(brow0 + k0 + k) * ldb + bcol0 + n0 + n, fB));
    }
    __syncthreads();
    s16x8 af[FM], bf[FN];
#pragma unroll
    for (int i = 0; i < FM; ++i)
      af[i] = *(const s16x8*)&As[wm * (BM / 2) + i * 16 + lm][q * 8];
#pragma unroll
    for (int j = 0; j < FN; ++j) {
      int nl = wn * (BN / 2) + j * 16 + lm;
      u16x8 tmp;
#pragma unroll
      for (int f = 0; f < 8; ++f) tmp[f] = Bs[q * 8 + f][nl];
      bf[j] = __builtin_bit_cast(s16x8, tmp);
    }
#pragma unroll
    for (int i = 0; i < FM; ++i)
#pragma unroll
      for (int j = 0; j < FN; ++j)
        acc[i][j] = __builtin_amdgcn_mfma_f32_16x16x32_bf16(af[i], bf[j], acc[i][j], 0, 0, 0);
  }
#pragma unroll
  for (int i = 0; i < FM; ++i) {
#pragma unroll
    for (int j = 0; j < FN; ++j) {
      const int col = wn * (BN / 2) + j * 16 + lm;
      float bb = 0.0f;
      if (EPI != 3 || addb) bb = ldx(bias, bias_off + n0 + col, fbias);
#pragma unroll
      for (int r = 0; r < 4; ++r) {
        const int rowg = m0 + wm * (BM / 2) + i * 16 + q * 4 + r;
        float v = acc[i][j][r] + bb;
        if constexpr (EPI == 0) {
          out_bf[(size_t)rowg * ldo + n0 + col] = f2bf(v);
        } else if constexpr (EPI == 1) {
          out_bf[(size_t)rowg * ldo + n0 + col] =
              f2bf(0.5f * v * (1.0f + erff(v * 0.70710678f)));
        } else if constexpr (EPI == 2) {
          const size_t off = (size_t)rowg * D_MODEL + n0 + col;
          yacc[off] = v + ldx(res, off, flags[ires]);
        } else {
          const size_t off = (size_t)rowg * D_MODEL + n0 + col;
          yacc[off] += v;
        }
      }
    }
  }
}

// ------------------------------------------------- attention (r14 coalesced-K)
// XCD-aware block swizzle (T1): neutral-vs-R0 at S=2048 but mechanistically
// sound (one head's 512 KB K/V slice per XCD L2) and harmless — kept.
__device__ __forceinline__ int key_index(int s, int j, int S) {
  int p;
  if (j < 64)       p = s + j - 32;
  else if (j < 102) p = s + (j - 83) * 64;
  else              p = ((j - 102) * (S - 1)) / 25;
  return min(max(p, 0), S - 1);
}

__global__ __launch_bounds__(256, 4)
void attn_kernel(const ushort_t* __restrict__ qkv, ushort_t* __restrict__ out, int S) {
  const int wave = threadIdx.x >> 6, lane = threadIdx.x & 63;
  const int nb = gridDim.x;
  int bid = blockIdx.x;
  if ((nb & 7) == 0) bid = (bid & 7) * (nb >> 3) + (bid >> 3);  // XCD swizzle (bijective)
  const int pair = bid * 4 + wave;          // pair = h*S + s
  const int h = pair / S;
  const int s = pair - h * S;
  const int g = lane >> 3, d8 = (lane & 7) * 8;

  int koff[16];
#pragma unroll
  for (int r = 0; r < 16; ++r)
    koff[r] = key_index(s, r * 8 + g, S) * (3 * D_MODEL);

  u16x8 qv8 = *(const u16x8*)(qkv + (size_t)s * (3 * D_MODEL) + h * HEAD_D + d8);
  float qf[8];
#pragma unroll
  for (int e = 0; e < 8; ++e) qf[e] = bf2f(qv8[e]);

  const ushort_t* kbase = qkv + D_MODEL + h * HEAD_D + d8;
  float pr[16];
  {
    u16x8 kv[8];
#pragma unroll
    for (int r = 0; r < 8; ++r) kv[r] = *(const u16x8*)(kbase + koff[r]);
#pragma unroll
    for (int r = 0; r < 16; ++r) {
      u16x8 cur = kv[r & 7];
      if (r < 8) kv[r & 7] = *(const u16x8*)(kbase + koff[r + 8]);
      float d = 0.f;
#pragma unroll
      for (int e = 0; e < 8; ++e) d += qf[e] * bf2f(cur[e]);
      d += __shfl_xor(d, 1);
      d += __shfl_xor(d, 2);
      d += __shfl_xor(d, 4);
      pr[r] = d * 0.125f;
    }
  }

  float mx = pr[0];
#pragma unroll
  for (int r = 1; r < 16; ++r) mx = fmaxf(mx, pr[r]);
#pragma unroll
  for (int m = 8; m <= 32; m <<= 1) mx = fmaxf(mx, __shfl_xor(mx, m));
  float sm = 0.f;
#pragma unroll
  for (int r = 0; r < 16; ++r) { pr[r] = __expf(pr[r] - mx); sm += pr[r]; }
#pragma unroll
  for (int m = 8; m <= 32; m <<= 1) sm += __shfl_xor(sm, m);
  const float inv = 1.0f / sm;

  const ushort_t* vbase = qkv + 2 * D_MODEL + h * HEAD_D + d8;
  float oacc[8];
#pragma unroll
  for (int e = 0; e < 8; ++e) oacc[e] = 0.f;
  {
    u16x8 vv[8];
#pragma unroll
    for (int r = 0; r < 8; ++r) vv[r] = *(const u16x8*)(vbase + koff[r]);
#pragma unroll
    for (int r = 0; r < 16; ++r) {
      u16x8 cv = vv[r & 7];
      float cp = pr[r] * inv;
      if (r < 8) vv[r & 7] = *(const u16x8*)(vbase + koff[r + 8]);
#pragma unroll
      for (int e = 0; e < 8; ++e) oacc[e] += cp * bf2f(cv[e]);
    }
  }
#pragma unroll
  for (int m = 8; m <= 32; m <<= 1)
#pragma unroll
    for (int e = 0; e < 8; ++e) oacc[e] += __shfl_xor(oacc[e], m);

  if (lane < 8) {
    u16x8 ov;
#pragma unroll
    for (int e = 0; e < 8; ++e) ov[e] = f2bf(oacc[e]);
    *(u16x8*)(out + (size_t)s * D_MODEL + h * HEAD_D + d8) = ov;
  }
}

// ------------------------------------------------- final convert (fallback only)
__global__ __launch_bounds__(256)
void convert_kernel(const float* __restrict__ y, void* __restrict__ out,
                    const int* __restrict__ flags, int n) {
  const int fout = flags[0];
  int i = blockIdx.x * 256 + threadIdx.x;
  if (i < n) {
    float v = y[i];
    if (fout) ((float*)out)[i] = v;
    else      ((ushort_t*)out)[i] = f2bf(v);
  }
}

// ------------------------------------------------- launch
extern "C" void kernel_launch(void* const* d_in, const int* in_sizes, int n_in,
                              void* d_out, int out_size, void* d_ws, size_t ws_size,
                              hipStream_t stream) {
  const int S = in_sizes[0] / D_MODEL;    // 2048
  const size_t sD = (size_t)S * D_MODEL;
  char* ws = (char*)d_ws;

  DetectArgs da;
  for (int i = 0; i < 14; ++i) { da.p[i] = d_in[i]; da.n[i] = in_sizes[i]; }

  ushort_t* h1    = (ushort_t*)d_out;
  ushort_t* attnb = (ushort_t*)d_out;
  ushort_t* h2    = (ushort_t*)d_out;

  const size_t MB = 1024 * 1024;
  if (ws_size >= 12 * MB + 64) {
    const int P  = (ws_size >= 20 * MB) ? 1 : 2;
    const int Nc = D_FFN / P;
    char* wbase = ws + (P == 1 ? 12 : 6) * MB;

    ushort_t* qkv   = (ushort_t*)ws;                       // [0,6M)
    float*    y     = (float*)ws;                          // [0,4M) after qkv dies
    ushort_t* gbuf  = (ushort_t*)(ws + 4 * MB);            // S*Nc bf16 (4 or 8 MB)
    ushort_t* wqkvT = (ushort_t*)wbase;                    // 1.5 MB
    ushort_t* woT   = (ushort_t*)(wbase + 1 * MB + 512 * 1024);  // 0.5 MB
    ushort_t* w1T   = (ushort_t*)(wbase + 2 * MB);         // 2 MB
    ushort_t* w2T   = (ushort_t*)(wbase + 4 * MB);         // 2 MB
    int*      flags = (int*)(wbase + 6 * MB);

    detect_all<<<14, 256, 0, stream>>>(da, flags);

    WDesc dq  = { d_in[6],  wqkvT, D_MODEL, 3 * D_MODEL, 6,  0 };
    WDesc dwo = { d_in[8],  woT,   D_MODEL, D_MODEL,     8,  768 };
    WDesc dw1 = { d_in[10], w1T,   D_MODEL, D_FFN,       10, 1024 };
    WDesc dw2 = { d_in[12], w2T,   D_FFN,   D_MODEL,     12, 2048 };

    // K2: weight convert (3072 blocks) + ln1 (S/4 blocks), flags-based
    prep_kernel<<<3072 + S / 4, 256, 0, stream>>>(
        dq, dwo, dw1, dw2, 3072, d_in[0], d_in[2], d_in[3], h1, flags);

    // GEMM1: h1 @ wqkv + bqkv -> qkv  (32x64, 1536 blocks, 6/CU)
    gemm_bt<32, 64, 0><<<dim3(24, S / 32), 256, 0, stream>>>(
        h1, D_MODEL, wqkvT, D_MODEL, D_MODEL, d_in[7], 0,
        nullptr, nullptr, qkv, 3 * D_MODEL, flags, 7, 0, 1);

    attn_kernel<<<(S * N_HEADS) / 4, 256, 0, stream>>>(qkv, attnb, S);

    // GEMM2: attnb @ wo + bo + x -> y (32x32, 1024 blocks, 4/CU)
    gemm_bt<32, 32, 2><<<dim3(16, S / 32), 256, 0, stream>>>(
        attnb, D_MODEL, woT, D_MODEL, D_MODEL, d_in[9], 0,
        d_in[0], y, nullptr, D_MODEL, flags, 9, 0, 1);

    ln2_kernel<<<S / 4, 256, 0, stream>>>(y, d_in[4], d_in[5], h2, flags);

    if (P == 1) {
      // GEMM3: h2 @ w1 + b1 -> gelu -> gbuf  (32x64, 2048 blocks, 8/CU)
      gemm_bt<32, 64, 1><<<dim3(D_FFN / 64, S / 32), 256, 0, stream>>>(
          h2, D_MODEL, w1T, D_MODEL, D_MODEL,
          d_in[11], 0, nullptr, nullptr, gbuf, D_FFN, flags, 11, 0, 1);
      // GEMM4: out = y + gbuf @ w2 + b2  (K=2048; 32x32, 1024 blocks, 4/CU)
      gemm_bt<32, 32, 4><<<dim3(16, S / 32), 256, 0, stream>>>(
          gbuf, D_FFN, w2T, D_FFN, D_FFN, d_in[13], 0,
          nullptr, y, (ushort_t*)d_out, D_MODEL, flags, 13, 0, 1);
    } else {
      gemm_bt<32, 64, 1><<<dim3(Nc / 64, S / 32), 256, 0, stream>>>(
          h2, D_MODEL, w1T, D_MODEL, D_MODEL,
          d_in[11], 0, nullptr, nullptr, gbuf, Nc, flags, 11, 0, 1);
      gemm_bt<32, 32, 3><<<dim3(16, S / 32), 256, 0, stream>>>(
          gbuf, Nc, w2T, D_FFN, Nc, d_in[13], 0,
          nullptr, y, nullptr, D_MODEL, flags, 13, 0, 1);
      gemm_bt<32, 64, 1><<<dim3(Nc / 64, S / 32), 256, 0, stream>>>(
          h2, D_MODEL, w1T + (size_t)Nc * D_MODEL, D_MODEL, D_MODEL,
          d_in[11], Nc, nullptr, nullptr, gbuf, Nc, flags, 11, 0, 1);
      gemm_bt<32, 32, 4><<<dim3(16, S / 32), 256, 0, stream>>>(
          gbuf, Nc, w2T + (size_t)Nc, D_FFN, Nc, d_in[13], 0,
          nullptr, y, (ushort_t*)d_out, D_MODEL, flags, 13, 0, 0);
    }
  } else {
    // fallback: round-6 proven path
    int P;
    if      (ws_size >= 12ull * MB + 4096) P = 1;
    else if (ws_size >=  8ull * MB + 4096) P = 2;
    else                                   P = 4;
    const int Nc = D_FFN / P;
    const size_t gbuf_bytes = (size_t)S * Nc * 2;
    const size_t qkv_bytes  = 3 * sD * 2;
    const size_t fo = 4ull * sD + gbuf_bytes;
    const size_t flags_pos = (qkv_bytes > fo ? qkv_bytes : fo);

    ushort_t* qkv  = (ushort_t*)ws;
    float*    y    = (float*)ws;
    ushort_t* gbuf = (ushort_t*)(ws + 4 * sD);
    int*      flags = (int*)(ws + flags_pos);

    detect_all<<<14, 256, 0, stream>>>(da, flags);
    ln1_kernel<<<S / 4, 256, 0, stream>>>(d_in[0], d_in[2], d_in[3], h1, flags);
    gemm_nn<128, 128, 0><<<dim3((3 * D_MODEL) / 128, S / 128), 256, 0, stream>>>(
        h1, D_MODEL, D_MODEL, d_in[6], 3 * D_MODEL, 0, 0, d_in[7], 0,
        nullptr, nullptr, qkv, 3 * D_MODEL, flags, 6, 7, 0, 1);
    attn_kernel<<<(S * N_HEADS) / 4, 256, 0, stream>>>(qkv, attnb, S);
    gemm_nn<64, 64, 2><<<dim3(D_MODEL / 64, S / 64), 256, 0, stream>>>(
        attnb, D_MODEL, D_MODEL, d_in[8], D_MODEL, 0, 0, d_in[9], 0,
        d_in[0], y, nullptr, D_MODEL, flags, 8, 9, 0, 1);
    ln2_kernel<<<S / 4, 256, 0, stream>>>(y, d_in[4], d_in[5], h2, flags);
    for (int p = 0; p < P; ++p) {
      if (Nc >= 1024) {
        gemm_nn<128, 128, 1><<<dim3(Nc / 128, S / 128), 256, 0, stream>>>(
            h2, D_MODEL, D_MODEL, d_in[10], D_FFN, 0, p * Nc, d_in[11], p * Nc,
            nullptr, nullptr, gbuf, Nc, flags, 10, 11, 0, 1);
      } else {
        gemm_nn<64, 64, 1><<<dim3(Nc / 64, S / 64), 256, 0, stream>>>(
            h2, D_MODEL, D_MODEL, d_in[10], D_FFN, 0, p * Nc, d_in[11], p * Nc,
            nullptr, nullptr, gbuf, Nc, flags, 10, 11, 0, 1);
      }
      gemm_nn<64, 64, 3><<<dim3(D_MODEL / 64, S / 64), 256, 0, stream>>>(
          gbuf, Nc, Nc, d_in[12], D_MODEL, p * Nc, 0, d_in[13], 0,
          nullptr, y, nullptr, D_MODEL, flags, 12, 13, 0, p == 0 ? 1 : 0);
    }
    convert_kernel<<<(int)((sD + 255) / 256), 256, 0, stream>>>(y, d_out, flags, (int)sD);
  }
}